// Round 1
// baseline (913.195 us; speedup 1.0000x reference)
//
#include <hip/hip_runtime.h>
#include <math.h>

// DTYPE COMMITMENTS (evidence-backed): inputs f32, output f32 (rounds 4-14 PASS).
// WS BUDGET: <= ~210 MB decimal; this build ~170 MiB.

#define T_ 16
#define N_ 64
#define NN_ 32
#define D_ 512
#define H_ 8
#define DK_ 64
#define DFF_ 2048
#define L_ 2
#define NPRED_ 20

typedef unsigned short u16;
typedef unsigned int u32;
typedef __attribute__((ext_vector_type(8))) short short8;
typedef __attribute__((ext_vector_type(4))) float f32x4;

__device__ __forceinline__ u16 f2bf(float f) {
    u32 u = __float_as_uint(f);
    u32 r = u + 0x7fffu + ((u >> 16) & 1u);
    return (u16)(r >> 16);
}
__device__ __forceinline__ float bfv(u16 v) {
    return __uint_as_float(((u32)v) << 16);
}
__device__ __forceinline__ float ntn(float v) {
    if (isnan(v)) return 0.0f;
    if (isinf(v)) return v > 0.0f ? 3.4028234663852886e38f : -3.4028234663852886e38f;
    return v;
}
__device__ __forceinline__ float wave_sum(float v) {
    #pragma unroll
    for (int o = 32; o > 0; o >>= 1) v += __shfl_xor(v, o, 64);
    return v;
}
// async 16B HBM->LDS: writes ldsbase + lane*16 (wave-uniform base, per-lane gptr)
__device__ __forceinline__ void gload_lds(const u16* g, u16* l) {
    __builtin_amdgcn_global_load_lds(
        (const __attribute__((address_space(1))) u32*)g,
        (__attribute__((address_space(3))) u32*)l, 16, 0, 0);
}

// ============ batched weight convert+transpose: 14 jobs in ONE launch ===============
struct WJob { const float* src; u16* dst; int K; int N; int t0; };
struct WJobs { WJob j[14]; };
__global__ __launch_bounds__(256) void wconv_all(WJobs jobs, int ntiles) {
    int bid = blockIdx.x;
    if (bid >= ntiles) return;
    int ji = 0;
    #pragma unroll 1
    for (int i = 1; i < 14; ++i) if (bid >= jobs.j[i].t0) ji = i;
    const float* in = jobs.j[ji].src;
    u16* out = jobs.j[ji].dst;
    int K = jobs.j[ji].K, N = jobs.j[ji].N;
    int lt = bid - jobs.j[ji].t0;
    int ntx = N >> 5;
    int nb = (lt % ntx) * 32, kb = (lt / ntx) * 32;
    __shared__ float tile[32][33];
    int tx = threadIdx.x & 31, ty = threadIdx.x >> 5;
    #pragma unroll
    for (int r = ty; r < 32; r += 8)
        tile[r][tx] = in[(size_t)(kb + r) * N + nb + tx];
    __syncthreads();
    #pragma unroll
    for (int r = ty; r < 32; r += 8)
        out[(size_t)(nb + r) * K + kb + tx] = f2bf(tile[tx][r]);
}

// ============ MFMA GEMM v3 + XCD-band remap (kept for small M=1024 GEMMs) ===========
// DMA staging + 3-bit XOR chunk swizzle (r9: 0 bank conflicts); XCD remap (r10).
// EPI: 0 none, 1 relu, 2 +res f32, 3 +res bf16.
template<int TM, int TN, int EPI, int WF32, int WBF16>
__global__ __launch_bounds__(256) void gemm_bt(
    const u16* __restrict__ Ab, const u16* __restrict__ Btb,
    float* __restrict__ Cf, u16* __restrict__ Cb, const void* __restrict__ Rg,
    int K, int ldc)
{
    constexpr int WR = TM / 32, WC = TN / 32;
    constexpr int ITA = TM / 32, ITB = TN / 32;
    __shared__ __align__(16) u16 As[TM][64];
    __shared__ __align__(16) u16 Bs[TN][64];
    int tid = threadIdx.x;
    int lane = tid & 63, wave = tid >> 6;
    int quad = lane >> 4, l16 = lane & 15;
    int wm = (wave >> 1) * (TM / 2), wn = (wave & 1) * (TN / 2);

    int gx = gridDim.x, gy = gridDim.y;
    int bx, by;
    if ((gy & 7) == 0) {
        int id = blockIdx.y * gx + blockIdx.x;
        int xcd = id & 7;
        int slot = id >> 3;
        bx = slot % gx;
        by = xcd * (gy >> 3) + slot / gx;
    } else {
        bx = blockIdx.x;
        by = blockIdx.y;
    }
    size_t row0 = (size_t)by * TM;
    size_t col0 = (size_t)bx * TN;

    f32x4 acc[WR][WC];
    #pragma unroll
    for (int i = 0; i < WR; ++i)
        #pragma unroll
        for (int j = 0; j < WC; ++j)
            acc[i][j] = (f32x4){0.f, 0.f, 0.f, 0.f};

    int srow = lane >> 3;
    int c8 = (lane & 7) ^ srow;
    int h8 = l16 & 7;

    for (int k0 = 0; k0 < K; k0 += 64) {
        __syncthreads();
        #pragma unroll
        for (int it = 0; it < ITA; ++it) {
            int g = wave + it * 4;
            gload_lds(Ab + (row0 + g * 8 + srow) * (size_t)K + k0 + c8 * 8, &As[g * 8][0]);
        }
        #pragma unroll
        for (int it = 0; it < ITB; ++it) {
            int g = wave + it * 4;
            gload_lds(Btb + (col0 + g * 8 + srow) * (size_t)K + k0 + c8 * 8, &Bs[g * 8][0]);
        }
        __syncthreads();
        #pragma unroll
        for (int s = 0; s < 2; ++s) {
            int coff = ((s * 4 + quad) ^ h8) * 8;   // full 3-bit XOR (r9-verified)
            short8 af[WR], bf[WC];
            #pragma unroll
            for (int i = 0; i < WR; ++i)
                af[i] = *(short8*)&As[wm + i * 16 + l16][coff];
            #pragma unroll
            for (int j = 0; j < WC; ++j)
                bf[j] = *(short8*)&Bs[wn + j * 16 + l16][coff];
            #pragma unroll
            for (int i = 0; i < WR; ++i)
                #pragma unroll
                for (int j = 0; j < WC; ++j)
                    acc[i][j] = __builtin_amdgcn_mfma_f32_16x16x32_bf16(
                        af[i], bf[j], acc[i][j], 0, 0, 0);
        }
    }
    // C/D layout (on-target verified): col = lane&15, row = quad*4 + reg
    #pragma unroll
    for (int i = 0; i < WR; ++i)
        #pragma unroll
        for (int j = 0; j < WC; ++j)
            #pragma unroll
            for (int reg = 0; reg < 4; ++reg) {
                size_t row = row0 + wm + i * 16 + quad * 4 + reg;
                size_t col = col0 + wn + j * 16 + l16;
                float v = acc[i][j][reg];
                if (EPI == 2) v += ((const float*)Rg)[row * (size_t)ldc + col];
                if (EPI == 3) v += bfv(((const u16*)Rg)[row * (size_t)ldc + col]);
                if (EPI == 1) v = fmaxf(v, 0.f);
                if (WF32)  Cf[row * (size_t)ldc + col] = v;
                if (WBF16) Cb[row * (size_t)ldc + col] = f2bf(v);
            }
}

// ============ 256x256 8-wave phase-split GEMM (double-buffered, aged prefetch) ======
// Structure per K-tile (64): 4 phases {ds_read 4-8 x b128; [phase0: issue ALL 8
// global_load_lds for tile t+1 -> other buffer]; s_barrier; setprio(1); 16 MFMA;
// setprio(0); s_barrier}, then ONE vmcnt(0)+barrier at the tile boundary. The 8
// prefetch loads are issued in phase 0 and drained ~3 phases (~1800 cyc) later, so
// the boundary drain is aged (counted-wait by construction: nothing younger in
// flight). Same verified 3-bit XOR chunk swizzle as gemm_bt (linear gload_lds dest,
// pre-swizzled global source, swizzled ds_read) -> 0 bank conflicts.
// Requires M%256==0, N%256==0, K%64==0, gridDim.y%8==0 (XCD remap).
template<int EPI, int WF32, int WBF16>
__global__ __launch_bounds__(512, 2) void gemm256_bt(
    const u16* __restrict__ Ab, const u16* __restrict__ Btb,
    float* __restrict__ Cf, u16* __restrict__ Cb, const void* __restrict__ Rg,
    int K, int ldc)
{
    __shared__ __align__(16) u16 As[2][256][64];
    __shared__ __align__(16) u16 Bs[2][256][64];
    int tid = threadIdx.x;
    int lane = tid & 63, wave = tid >> 6;        // 8 waves: 2M x 4N
    int quad = lane >> 4, l16 = lane & 15;
    int wm = (wave >> 2) * 128, wn = (wave & 3) * 64;

    int gx = gridDim.x, gy = gridDim.y;
    int id = blockIdx.y * gx + blockIdx.x;
    int xcd = id & 7, slot = id >> 3;
    int bx = slot % gx;
    int by = xcd * (gy >> 3) + slot / gx;
    size_t row0 = (size_t)by * 256;
    size_t col0 = (size_t)bx * 256;

    f32x4 acc[8][4];
    #pragma unroll
    for (int i = 0; i < 8; ++i)
        #pragma unroll
        for (int j = 0; j < 4; ++j)
            acc[i][j] = (f32x4){0.f, 0.f, 0.f, 0.f};

    int srow = lane >> 3;
    int c8 = (lane & 7) ^ srow;                  // source pre-swizzle
    int h8 = l16 & 7;

    // per-thread global element offsets for staging (it = 0..3 covers 32 row-groups)
    size_t aoff[4], boff[4];
    #pragma unroll
    for (int it = 0; it < 4; ++it) {
        int g = wave + it * 8;
        aoff[it] = (row0 + (size_t)g * 8 + srow) * (size_t)K + c8 * 8;
        boff[it] = (col0 + (size_t)g * 8 + srow) * (size_t)K + c8 * 8;
    }

    // prologue: stage tile 0 into buffer 0, drain, converge
    #pragma unroll
    for (int it = 0; it < 4; ++it)
        gload_lds(Ab + aoff[it], &As[0][(wave + it * 8) * 8][0]);
    #pragma unroll
    for (int it = 0; it < 4; ++it)
        gload_lds(Btb + boff[it], &Bs[0][(wave + it * 8) * 8][0]);
    asm volatile("s_waitcnt vmcnt(0)" ::: "memory");
    __builtin_amdgcn_s_barrier();

    int nt = K >> 6;
    #pragma unroll 1
    for (int t = 0; t < nt; ++t) {
        int cur = t & 1, nxt = cur ^ 1;
        size_t knext = (size_t)(t + 1) * 64;
        short8 af[4], bf[4];
        #pragma unroll
        for (int kh = 0; kh < 2; ++kh) {
            #pragma unroll
            for (int mh = 0; mh < 2; ++mh) {
                int coff = ((kh * 4 + quad) ^ h8) * 8;
                if (mh == 0) {                       // B frags reused across mh
                    #pragma unroll
                    for (int j = 0; j < 4; ++j)
                        bf[j] = *(short8*)&Bs[cur][wn + j * 16 + l16][coff];
                }
                #pragma unroll
                for (int i = 0; i < 4; ++i)
                    af[i] = *(short8*)&As[cur][wm + (mh * 4 + i) * 16 + l16][coff];
                if (kh == 0 && mh == 0 && t + 1 < nt) {
                    // burst-issue next tile's 8 staging loads (aged by ~3 phases)
                    #pragma unroll
                    for (int it = 0; it < 4; ++it)
                        gload_lds(Ab + aoff[it] + knext, &As[nxt][(wave + it * 8) * 8][0]);
                    #pragma unroll
                    for (int it = 0; it < 4; ++it)
                        gload_lds(Btb + boff[it] + knext, &Bs[nxt][(wave + it * 8) * 8][0]);
                }
                __builtin_amdgcn_s_barrier();
                __builtin_amdgcn_s_setprio(1);
                #pragma unroll
                for (int i = 0; i < 4; ++i)
                    #pragma unroll
                    for (int j = 0; j < 4; ++j)
                        acc[mh * 4 + i][j] = __builtin_amdgcn_mfma_f32_16x16x32_bf16(
                            af[i], bf[j], acc[mh * 4 + i][j], 0, 0, 0);
                __builtin_amdgcn_s_setprio(0);
                __builtin_amdgcn_s_barrier();
            }
        }
        // tile boundary: only outstanding VMEM is next tile's 8 loads (issued phase 0)
        asm volatile("s_waitcnt vmcnt(0)" ::: "memory");
        __builtin_amdgcn_s_barrier();
    }

    // C/D layout: col = lane&15, row = quad*4 + reg
    #pragma unroll
    for (int i = 0; i < 8; ++i)
        #pragma unroll
        for (int j = 0; j < 4; ++j)
            #pragma unroll
            for (int reg = 0; reg < 4; ++reg) {
                size_t row = row0 + wm + i * 16 + quad * 4 + reg;
                size_t col = col0 + wn + j * 16 + l16;
                float v = acc[i][j][reg];
                if (EPI == 2) v += ((const float*)Rg)[row * (size_t)ldc + col];
                if (EPI == 3) v += bfv(((const u16*)Rg)[row * (size_t)ldc + col]);
                if (EPI == 1) v = fmaxf(v, 0.f);
                if (WF32)  Cf[row * (size_t)ldc + col] = v;
                if (WBF16) Cb[row * (size_t)ldc + col] = f2bf(v);
            }
}

// ============ fused attention per (b,m): all-heads phases, 3 barriers ===============
template<int CTX, int LD>
__global__ __launch_bounds__(256) void attn_fused_kernel(
    const u16* __restrict__ QKVb, const float* __restrict__ maskf, int bm0,
    float* __restrict__ att_sum, u16* __restrict__ ctxb)
{
    __shared__ __align__(16) u16 sQ[16][520];
    __shared__ __align__(16) u16 sK[16][520];
    __shared__ __align__(16) u16 sV[CTX ? 16 : 1][520];
    __shared__ float s_p[H_][16][17];
    int bm_l = blockIdx.x;
    int tid = threadIdx.x;
    int t = tid >> 4, ch = (tid & 15) * 32;
    const u16* base = QKVb + ((size_t)bm_l * T_ + t) * LD;
    #pragma unroll
    for (int c = 0; c < 4; ++c) {
        *(uint4*)&sQ[t][ch + c * 8] = *(const uint4*)(base + ch + c * 8);
        *(uint4*)&sK[t][ch + c * 8] = *(const uint4*)(base + 512 + ch + c * 8);
        if (CTX) *(uint4*)&sV[t][ch + c * 8] = *(const uint4*)(base + 1024 + ch + c * 8);
    }
    __syncthreads();

    int b = (bm0 + bm_l) >> 5;                  // bm = b*NN + m

    #pragma unroll
    for (int r = 0; r < 8; ++r) {
        int h = r;
        int q = (tid >> 4) & 15, k = tid & 15;
        const u32* qu = (const u32*)&sQ[q][0] + h * 32;
        const u32* ku = (const u32*)&sK[k][0] + h * 32;
        float acc = 0.f;
        #pragma unroll
        for (int j = 0; j < 32; ++j) {
            u32 a = qu[j], bb = ku[j];
            acc += bfv((u16)(a & 0xffff)) * bfv((u16)(bb & 0xffff));
            acc += bfv((u16)(a >> 16))    * bfv((u16)(bb >> 16));
        }
        acc *= 0.125f;
        if (maskf[(size_t)(bm0 + bm_l) * T_ + q] == 0.0f) acc = -1e9f;
        s_p[h][q][k] = acc;
    }
    __syncthreads();
    if (tid < 128) {
        int h = tid >> 4, q = tid & 15;
        float mx = -3.4e38f;
        #pragma unroll
        for (int kk = 0; kk < 16; ++kk) mx = fmaxf(mx, s_p[h][q][kk]);
        float e[16], s = 0.f;
        #pragma unroll
        for (int kk = 0; kk < 16; ++kk) { e[kk] = expf(s_p[h][q][kk] - mx); s += e[kk]; }
        float inv = 1.0f / s;
        #pragma unroll
        for (int kk = 0; kk < 16; ++kk) s_p[h][q][kk] = e[kk] * inv;
    }
    __syncthreads();
    #pragma unroll
    for (int r = 0; r < 8; ++r) {
        int h = r;
        int q = (tid >> 4) & 15, k = tid & 15;
        atomicAdd(&att_sum[(((size_t)b * H_ + h) * T_ + q) * T_ + k], s_p[h][q][k]);
    }
    if (CTX) {
        #pragma unroll
        for (int rep = 0; rep < 16; ++rep) {
            int i2 = rep * 256 + tid;           // t*256 + c2, c2 = (h*64+dk)/2
            int tt = i2 >> 8, c2 = i2 & 255;
            int h = c2 >> 5;
            const float* pr = &s_p[h][tt][0];
            float a0 = 0.f, a1 = 0.f;
            #pragma unroll
            for (int kk = 0; kk < 16; ++kk) {
                u32 vv = *((const u32*)&sV[kk][0] + c2);
                float p = pr[kk];
                a0 += p * bfv((u16)(vv & 0xffff));
                a1 += p * bfv((u16)(vv >> 16));
            }
            u32 o = (u32)f2bf(a0) | ((u32)f2bf(a1) << 16);
            *((u32*)(ctxb + ((size_t)bm_l * T_ + tt) * D_) + c2) = o;
        }
    }
}

// ============ fused self-attention + combine + si, one block per (n,h) ==============
__global__ __launch_bounds__(256) void siatt_kernel(
    const float* __restrict__ xemb, const float* __restrict__ att_sum,
    const float* __restrict__ attf, u16* __restrict__ sib)
{
    __shared__ float sX[16][516];
    __shared__ float sS[16][17];
    __shared__ float sA[16][17];
    int n = blockIdx.x >> 3, h = blockIdx.x & 7;
    int tid = threadIdx.x;
    int t = tid >> 4, ch = (tid & 15) * 32;
    const float* src = xemb + ((size_t)n * T_ + t) * D_;
    #pragma unroll
    for (int c = 0; c < 8; ++c)
        *(float4*)&sX[t][ch + c * 4] = *(const float4*)(src + ch + c * 4);
    __syncthreads();
    int q = tid >> 4, k = tid & 15;
    {
        float acc = 0.f;
        for (int d = 0; d < D_; ++d) acc += sX[q][d] * sX[k][d];
        sS[q][k] = acc * 0.04419417382415922f;
    }
    __syncthreads();
    if (tid < T_) {
        float mx = -3.4e38f;
        #pragma unroll
        for (int kk = 0; kk < 16; ++kk) mx = fmaxf(mx, sS[tid][kk]);
        float e[16], s = 0.f;
        #pragma unroll
        for (int kk = 0; kk < 16; ++kk) { e[kk] = expf(sS[tid][kk] - mx); s += e[kk]; }
        float inv = 1.0f / s;
        #pragma unroll
        for (int kk = 0; kk < 16; ++kk) sS[tid][kk] = e[kk] * inv;
    }
    __syncthreads();
    float f = attf[0] * (1.0f / 32.0f);
    sA[q][k] = sS[q][k] + f * att_sum[((size_t)n * H_ + h) * 256 + q * 16 + k];
    __syncthreads();
    #pragma unroll
    for (int rep = 0; rep < 16; ++rep) {
        int i2 = rep * 256 + tid;          // q*256 + d2
        int qq = i2 >> 8, d2 = (i2 & 255) * 2;
        const float* ar = &sA[qq][0];
        float a0 = 0.f, a1 = 0.f;
        #pragma unroll
        for (int tt = 0; tt < 16; ++tt) {
            float p = ar[tt];
            a0 += p * sX[tt][d2];
            a1 += p * sX[tt][d2 + 1];
        }
        u32 o = (u32)f2bf(a0) | ((u32)f2bf(a1) << 16);
        *((u32*)(sib + (size_t)n * T_ * 4096 + (size_t)qq * 4096 + h * 512) + (d2 >> 1)) = o;
    }
}

// ---------------- positional encoding ------------------------------------------------
__global__ void pe_kernel(float* pe) {
    int i = blockIdx.x * blockDim.x + threadIdx.x;
    if (i >= T_ * 256) return;
    int t = i >> 8, j = i & 255;
    float dv = (float)pow(10000.0, (double)j / 256.0);
    float a = (float)t * dv;
    double ad = (double)a;
    pe[t * D_ + 2 * j]     = (float)sin(ad);
    pe[t * D_ + 2 * j + 1] = (float)cos(ad);
}

// ---------------- x features + embed -------------------------------------------------
__global__ void xemb_kernel(const float* x, const float* Wx, const float* bx,
                            const float* pe, float* xemb) {
    int row = blockIdx.x;              // t*N + n
    int t = row / N_, n = row % N_;
    float x0 = x[row * 6 + 0], x1 = x[row * 6 + 1];
    float x2 = x[row * 6 + 2], x3 = x[row * 6 + 3];
    float x4 = x[row * 6 + 4], x5 = x[row * 6 + 5];
    float vel = sqrtf(x2 * x2 + x3 * x3);
    float ang = atanf(x5 / x4);
    float f0 = ntn(x0), f1 = ntn(x1), f2 = ntn(vel), f3 = ntn(ang);
    for (int d = threadIdx.x; d < D_; d += blockDim.x) {
        xemb[((size_t)n * T_ + t) * D_ + d] =
            f0 * Wx[0 * D_ + d] + f1 * Wx[1 * D_ + d]
          + f2 * Wx[2 * D_ + d] + f3 * Wx[3 * D_ + d]
          + bx[d] + pe[t * D_ + d];
    }
}

// ---------------- neighbor features + mask -------------------------------------------
__global__ void nbr_kernel(const float* x, const float* nbr, float* nf, float* maskf) {
    int idx = blockIdx.x * blockDim.x + threadIdx.x;   // t*N*NN + n*NN + m
    if (idx >= T_ * N_ * NN_) return;
    int m = idx % NN_;
    int tn = idx / NN_;
    int n = tn % N_, t = tn / N_;
    float px = x[((size_t)t * N_ + n) * 6 + 0];
    float py = x[((size_t)t * N_ + n) * 6 + 1];
    float vx, vy;
    if (t == 0) {
        vx = x[((size_t)1 * N_ + n) * 6 + 2];
        vy = x[((size_t)1 * N_ + n) * 6 + 3];
    } else {
        vx = px - x[((size_t)(t - 1) * N_ + n) * 6 + 0];
        vy = py - x[((size_t)(t - 1) * N_ + n) * 6 + 1];
    }
    float nx  = nbr[(size_t)idx * 4 + 0], ny  = nbr[(size_t)idx * 4 + 1];
    float nvx = nbr[(size_t)idx * 4 + 2], nvy = nbr[(size_t)idx * 4 + 3];
    float dpx = nx - px, dpy = ny - py;
    float dvx = nvx - vx, dvy = nvy - vy;
    float dist = sqrtf(dpx * dpx + dpy * dpy);
    maskf[((size_t)n * NN_ + m) * T_ + t] = (dist <= 2.0f) ? 1.0f : 0.0f;
    float vn = sqrtf(vx * vx + vy * vy);
    float bearing = (dpx * vx + dpy * vy) / (dist * vn);
    if (isnan(bearing)) bearing = 0.0f;
    float dvn = sqrtf(dvx * dvx + dvy * dvy);
    float tau = -(dpx * dvx + dpy * dvy) / dvn;
    if (isnan(tau)) tau = 0.0f;
    tau = fminf(fmaxf(tau, 0.0f), 7.0f);
    float mx_ = dpx + tau * dvx, my_ = dpy + tau * dvy;
    float mpd = sqrtf(mx_ * mx_ + my_ * my_);
    nf[(size_t)idx * 3 + 0] = ntn(dist);
    nf[(size_t)idx * 3 + 1] = ntn(bearing);
    nf[(size_t)idx * 3 + 2] = ntn(mpd);
}

// ---------------- neighbor embed: bf16 n_emb only ------------------------------------
__global__ void nemb_kernel(const float* nf, const float* Wn, const float* bn,
                            const float* pe, u16* Ab) {
    int row = blockIdx.x;              // (b*NN+m)*T + t
    int t = row % T_;
    int bm = row / T_;
    int m = bm % NN_, b = bm / NN_;
    size_t nfrow = (((size_t)t * N_ + b) * NN_ + m) * 3;
    float f0 = nf[nfrow], f1 = nf[nfrow + 1], f2 = nf[nfrow + 2];
    for (int d = threadIdx.x; d < D_; d += blockDim.x) {
        float v = f0 * Wn[d] + f1 * Wn[D_ + d] + f2 * Wn[2 * D_ + d]
                + bn[d] + pe[t * D_ + d];
        Ab[(size_t)row * D_ + d] = f2bf(v);
    }
}

// ---------------- LayerNorm, one wave per row; input f32 or bf16; dual out -----------
template<int INBF>
__global__ __launch_bounds__(256) void ln_kernel(
    const void* X, const float* g, const float* b, float* outF, u16* outB, int nrows) {
    int row = blockIdx.x * 4 + (threadIdx.x >> 6);
    if (row >= nrows) return;
    int lane = threadIdx.x & 63;
    float v[8];
    float s = 0.f;
    #pragma unroll
    for (int r = 0; r < 8; ++r) {
        int d = lane + r * 64;
        v[r] = INBF ? bfv(((const u16*)X)[(size_t)row * D_ + d])
                    : ((const float*)X)[(size_t)row * D_ + d];
        s += v[r];
    }
    s = wave_sum(s);
    float mean = s * (1.0f / 512.0f);
    float vs = 0.f;
    #pragma unroll
    for (int r = 0; r < 8; ++r) { float d = v[r] - mean; vs += d * d; }
    vs = wave_sum(vs);
    float rstd = rsqrtf(vs * (1.0f / 512.0f) + 1e-5f);
    #pragma unroll
    for (int r = 0; r < 8; ++r) {
        int d = lane + r * 64;
        float o = (v[r] - mean) * rstd * g[d] + b[d];
        if (outF) outF[(size_t)row * D_ + d] = o;
        if (outB) outB[(size_t)row * D_ + d] = f2bf(o);
    }
}

// ---------------- prediction head + broadcast fused (f32 out) ------------------------
__global__ void predbcast_kernel(const float* xemb, const float* Wp, const float* bp,
                                 float* out) {
    int idx = blockIdx.x * blockDim.x + threadIdx.x;   // (n*T+t)*2 + c
    if (idx >= N_ * T_ * 2) return;
    int c = idx & 1;
    int nt = idx >> 1;
    int n = nt / T_, t = nt % T_;
    float acc = bp[c];
    for (int j = 0; j < D_; ++j) acc += xemb[(size_t)nt * D_ + j] * Wp[(size_t)j * 2 + c];
    #pragma unroll
    for (int p = 0; p < NPRED_; ++p)
        out[(((size_t)p * T_ + t) * N_ + n) * 2 + c] = acc;
}

extern "C" void kernel_launch(void* const* d_in, const int* in_sizes, int n_in,
                              void* d_out, int out_size, void* d_ws, size_t ws_size,
                              hipStream_t stream) {
    (void)in_sizes; (void)n_in; (void)out_size; (void)ws_size;

    const float* x    = (const float*)d_in[0];
    const float* nbr  = (const float*)d_in[1];
    const float* attf = (const float*)d_in[2];
    const float* Wx   = (const float*)d_in[3];
    const float* bx   = (const float*)d_in[4];
    const float* Wn   = (const float*)d_in[5];
    const float* bn   = (const float*)d_in[6];
    const float* Wp   = (const float*)d_in[7];
    const float* bp   = (const float*)d_in[8];
    const float* WQ   = (const float*)d_in[9];
    const float* WK   = (const float*)d_in[10];
    const float* WV   = (const float*)d_in[11];
    const float* Wfc  = (const float*)d_in[12];
    const float* mlng = (const float*)d_in[13];
    const float* mlnb = (const float*)d_in[14];
    const float* WSI  = (const float*)d_in[15];
    const float* fsw1 = (const float*)d_in[16];
    const float* fsw2 = (const float*)d_in[17];
    const float* fsg  = (const float*)d_in[18];
    const float* fsb  = (const float*)d_in[19];
    const float* fiw1 = (const float*)d_in[20];
    const float* fiw2 = (const float*)d_in[21];
    const float* fig  = (const float*)d_in[22];
    const float* fib  = (const float*)d_in[23];

    char* w = (char*)d_ws;
    size_t off = 0;
    auto alloc = [&](size_t bytes) -> void* {
        void* p = w + off;
        off = (off + bytes + 255) & ~(size_t)255;
        return p;
    };
    const size_t MiB = 1024 * 1024;

    const int BM = N_ * NN_;          // 2048 (b,m) pairs
    const int ROWS_I = BM * T_;       // 32768 neighbor rows
    const int CB = 1024;              // bm per chunk (NCH=2, l=0 only)
    const int RC = CB * T_;           // 16384 rows per chunk
    const int NCH = ROWS_I / RC;      // 2

    float* pe      = (float*)alloc((size_t)T_ * D_ * 4);
    float* xemb    = (float*)alloc((size_t)N_ * T_ * D_ * 4);
    float* nf      = (float*)alloc((size_t)T_ * N_ * NN_ * 3 * 4);
    float* maskf   = (float*)alloc((size_t)BM * T_ * 4);
    u16*   Ab      = (u16*)alloc((size_t)ROWS_I * D_ * 2);     // n_emb bf16  32 MiB
    u16* tQKV[2], *tWSI[2], *tfs1[2], *tfs2[2];
    for (int l = 0; l < 2; ++l) {
        tQKV[l] = (u16*)alloc((size_t)1536 * 512 * 2);
        tWSI[l] = (u16*)alloc((size_t)512 * 4096 * 2);
        tfs1[l] = (u16*)alloc((size_t)2048 * 512 * 2);
        tfs2[l] = (u16*)alloc((size_t)512 * 2048 * 2);
    }
    u16* tWfc = (u16*)alloc((size_t)512 * 512 * 2);
    u16* tfi1 = (u16*)alloc((size_t)2048 * 512 * 2);
    u16* tfi2 = (u16*)alloc((size_t)512 * 2048 * 2);
    // scratch union: l0 chunk: QKVb 48 + ctxb 16 | hid 64 ; l1: QK full 64 MiB
    char* SCR  = (char*)alloc(64 * MiB);
    u16*   QKVb = (u16*)SCR;
    u16*   ctxb = (u16*)(SCR + 48 * MiB);
    u16*   hid  = (u16*)SCR;
    u16*   BbA    = (u16*)alloc((size_t)RC * D_ * 2);  // pre-LN bf16 chunk    16 MiB
    u16*   Bb_res = (u16*)alloc((size_t)RC * D_ * 2);  // res_inter bf16       16 MiB
    float* att_sum = (float*)alloc((size_t)N_ * H_ * 256 * 4);
    u16*   sib     = (u16*)alloc((size_t)N_ * T_ * 4096 * 2);  // 8 MiB
    float* xnew    = (float*)alloc((size_t)N_ * T_ * D_ * 4);
    u16*   xnb     = (u16*)alloc((size_t)N_ * T_ * D_ * 2);
    // total ~170 MiB

    // ---- batched weight conversion: 14 jobs, one launch ----
    WJobs jobs;
    int ntiles = 0;
    auto addJob = [&](int idx, const float* src, u16* dst, int K, int N) {
        jobs.j[idx] = {src, dst, K, N, ntiles};
        ntiles += (N >> 5) * (K >> 5);
    };
    addJob(0,  WQ,                            tQKV[0],              512, 512);
    addJob(1,  WK,                            tQKV[0] + 512 * 512,  512, 512);
    addJob(2,  WV,                            tQKV[0] + 1024 * 512, 512, 512);   // dead at l=1
    addJob(3,  WQ + (size_t)512 * 512,        tQKV[1],              512, 512);
    addJob(4,  WK + (size_t)512 * 512,        tQKV[1] + 512 * 512,  512, 512);
    addJob(5,  Wfc,                           tWfc,                 512, 512);
    addJob(6,  WSI,                           tWSI[0],              4096, 512);
    addJob(7,  WSI + (size_t)4096 * 512,      tWSI[1],              4096, 512);
    addJob(8,  fsw1,                          tfs1[0],              512, 2048);
    addJob(9,  fsw1 + (size_t)512 * 2048,     tfs1[1],              512, 2048);
    addJob(10, fsw2,                          tfs2[0],              2048, 512);
    addJob(11, fsw2 + (size_t)2048 * 512,     tfs2[1],              2048, 512);
    addJob(12, fiw1,                          tfi1,                 512, 2048);
    addJob(13, fiw2,                          tfi2,                 2048, 512);
    wconv_all<<<ntiles, 256, 0, stream>>>(jobs, ntiles);

    pe_kernel<<<16, 256, 0, stream>>>(pe);
    xemb_kernel<<<T_ * N_, 256, 0, stream>>>(x, Wx, bx, pe, xemb);
    nbr_kernel<<<(T_ * N_ * NN_ + 255) / 256, 256, 0, stream>>>(x, nbr, nf, maskf);
    nemb_kernel<<<BM * T_, 256, 0, stream>>>(nf, Wn, bn, pe, Ab);

    for (int l = 0; l < L_; ++l) {
        hipMemsetAsync(att_sum, 0, (size_t)N_ * H_ * 256 * 4, stream);
        if (l == 0) {
            for (int c = 0; c < NCH; ++c) {
                u16* Acb = Ab + (size_t)c * RC * D_;
                // QKV fused GEMM: N=1536, 256x256 (384 blocks)
                gemm256_bt<0, 0, 1><<<dim3(6, RC / 256), 512, 0, stream>>>(
                    Acb, tQKV[0], nullptr, QKVb, nullptr, 512, 1536);
                attn_fused_kernel<1, 1536><<<CB, 256, 0, stream>>>(
                    QKVb, maskf, c * CB, att_sum, ctxb);
                // fc + residual(n_emb bf16) -> pre-LN bf16
                gemm256_bt<3, 0, 1><<<dim3(2, RC / 256), 512, 0, stream>>>(
                    ctxb, tWfc, nullptr, BbA, Acb, 512, 512);
                ln_kernel<1><<<RC / 4, 256, 0, stream>>>(
                    BbA, mlng, mlnb, nullptr, Bb_res, RC);   // res_inter bf16
                // ffi1 relu: N=2048, 256x256 (512 blocks); hid aliases QKVb/ctxb
                gemm256_bt<1, 0, 1><<<dim3(8, RC / 256), 512, 0, stream>>>(
                    Bb_res, tfi1, nullptr, hid, nullptr, 512, 2048);
                // ffi2 + residual(res_inter bf16) -> pre-LN bf16
                gemm256_bt<3, 0, 1><<<dim3(2, RC / 256), 512, 0, stream>>>(
                    hid, tfi2, nullptr, BbA, Bb_res, 2048, 512);
                ln_kernel<1><<<RC / 4, 256, 0, stream>>>(
                    BbA, fig, fib, nullptr, Acb, RC);        // new n_emb (bf16)
            }
        } else {
            // l=1: unchunked QK (N=1024, ldc=1024; 64 MiB = SCR) + one attn pass
            gemm256_bt<0, 0, 1><<<dim3(4, ROWS_I / 256), 512, 0, stream>>>(
                Ab, tQKV[1], nullptr, QKVb, nullptr, 512, 1024);
            attn_fused_kernel<0, 1024><<<BM, 256, 0, stream>>>(
                QKVb, maskf, 0, att_sum, nullptr);
        }

        // ---- self-attention + si + ffs (updates xemb; f32 chain unchanged) ----
        siatt_kernel<<<N_ * H_, 256, 0, stream>>>(xemb, att_sum, attf, sib);
        gemm_bt<32, 64, 0, 1, 1><<<dim3(8, 32), 256, 0, stream>>>(
            sib, tWSI[l], xnew, xnb, nullptr, 4096, 512);
        gemm_bt<32, 64, 1, 0, 1><<<dim3(32, 32), 256, 0, stream>>>(
            xnb, tfs1[l], nullptr, hid, nullptr, 512, 2048);
        gemm_bt<32, 64, 2, 1, 0><<<dim3(8, 32), 256, 0, stream>>>(
            hid, tfs2[l], xemb, nullptr, xnew, 2048, 512);
        ln_kernel<0><<<(N_ * T_) / 4, 256, 0, stream>>>(
            xemb, fsg + l * D_, fsb + l * D_, xemb, nullptr, N_ * T_);
    }

    predbcast_kernel<<<(N_ * T_ * 2 + 255) / 256, 256, 0, stream>>>(
        xemb, Wp, bp, (float*)d_out);
}

// Round 2
// 899.348 us; speedup vs baseline: 1.0154x; 1.0154x over previous
//
#include <hip/hip_runtime.h>
#include <math.h>

// DTYPE COMMITMENTS (evidence-backed): inputs f32, output f32 (rounds 4-14 PASS).
// WS BUDGET: <= ~210 MB decimal; this build ~170 MiB.

#define T_ 16
#define N_ 64
#define NN_ 32
#define D_ 512
#define H_ 8
#define DK_ 64
#define DFF_ 2048
#define L_ 2
#define NPRED_ 20

typedef unsigned short u16;
typedef unsigned int u32;
typedef __attribute__((ext_vector_type(8))) short short8;
typedef __attribute__((ext_vector_type(4))) float f32x4;

__device__ __forceinline__ u16 f2bf(float f) {
    u32 u = __float_as_uint(f);
    u32 r = u + 0x7fffu + ((u >> 16) & 1u);
    return (u16)(r >> 16);
}
__device__ __forceinline__ float bfv(u16 v) {
    return __uint_as_float(((u32)v) << 16);
}
__device__ __forceinline__ float ntn(float v) {
    if (isnan(v)) return 0.0f;
    if (isinf(v)) return v > 0.0f ? 3.4028234663852886e38f : -3.4028234663852886e38f;
    return v;
}
__device__ __forceinline__ float wave_sum(float v) {
    #pragma unroll
    for (int o = 32; o > 0; o >>= 1) v += __shfl_xor(v, o, 64);
    return v;
}
// async 16B HBM->LDS: writes ldsbase + lane*16 (wave-uniform base, per-lane gptr)
__device__ __forceinline__ void gload_lds(const u16* g, u16* l) {
    __builtin_amdgcn_global_load_lds(
        (const __attribute__((address_space(1))) u32*)g,
        (__attribute__((address_space(3))) u32*)l, 16, 0, 0);
}

// ============ batched weight convert+transpose: 14 jobs in ONE launch ===============
struct WJob { const float* src; u16* dst; int K; int N; int t0; };
struct WJobs { WJob j[14]; };
__global__ __launch_bounds__(256) void wconv_all(WJobs jobs, int ntiles) {
    int bid = blockIdx.x;
    if (bid >= ntiles) return;
    int ji = 0;
    #pragma unroll 1
    for (int i = 1; i < 14; ++i) if (bid >= jobs.j[i].t0) ji = i;
    const float* in = jobs.j[ji].src;
    u16* out = jobs.j[ji].dst;
    int K = jobs.j[ji].K, N = jobs.j[ji].N;
    int lt = bid - jobs.j[ji].t0;
    int ntx = N >> 5;
    int nb = (lt % ntx) * 32, kb = (lt / ntx) * 32;
    __shared__ float tile[32][33];
    int tx = threadIdx.x & 31, ty = threadIdx.x >> 5;
    #pragma unroll
    for (int r = ty; r < 32; r += 8)
        tile[r][tx] = in[(size_t)(kb + r) * N + nb + tx];
    __syncthreads();
    #pragma unroll
    for (int r = ty; r < 32; r += 8)
        out[(size_t)(nb + r) * K + kb + tx] = f2bf(tile[tx][r]);
}

// ============ MFMA GEMM v3 + XCD-band remap (kept for small M=1024 GEMMs) ===========
// DMA staging + 3-bit XOR chunk swizzle (r9: 0 bank conflicts); XCD remap (r10).
// EPI: 0 none, 1 relu, 2 +res f32, 3 +res bf16.
template<int TM, int TN, int EPI, int WF32, int WBF16>
__global__ __launch_bounds__(256) void gemm_bt(
    const u16* __restrict__ Ab, const u16* __restrict__ Btb,
    float* __restrict__ Cf, u16* __restrict__ Cb, const void* __restrict__ Rg,
    int K, int ldc)
{
    constexpr int WR = TM / 32, WC = TN / 32;
    constexpr int ITA = TM / 32, ITB = TN / 32;
    __shared__ __align__(16) u16 As[TM][64];
    __shared__ __align__(16) u16 Bs[TN][64];
    int tid = threadIdx.x;
    int lane = tid & 63, wave = tid >> 6;
    int quad = lane >> 4, l16 = lane & 15;
    int wm = (wave >> 1) * (TM / 2), wn = (wave & 1) * (TN / 2);

    int gx = gridDim.x, gy = gridDim.y;
    int bx, by;
    if ((gy & 7) == 0) {
        int id = blockIdx.y * gx + blockIdx.x;
        int xcd = id & 7;
        int slot = id >> 3;
        bx = slot % gx;
        by = xcd * (gy >> 3) + slot / gx;
    } else {
        bx = blockIdx.x;
        by = blockIdx.y;
    }
    size_t row0 = (size_t)by * TM;
    size_t col0 = (size_t)bx * TN;

    f32x4 acc[WR][WC];
    #pragma unroll
    for (int i = 0; i < WR; ++i)
        #pragma unroll
        for (int j = 0; j < WC; ++j)
            acc[i][j] = (f32x4){0.f, 0.f, 0.f, 0.f};

    int srow = lane >> 3;
    int c8 = (lane & 7) ^ srow;
    int h8 = l16 & 7;

    for (int k0 = 0; k0 < K; k0 += 64) {
        __syncthreads();
        #pragma unroll
        for (int it = 0; it < ITA; ++it) {
            int g = wave + it * 4;
            gload_lds(Ab + (row0 + g * 8 + srow) * (size_t)K + k0 + c8 * 8, &As[g * 8][0]);
        }
        #pragma unroll
        for (int it = 0; it < ITB; ++it) {
            int g = wave + it * 4;
            gload_lds(Btb + (col0 + g * 8 + srow) * (size_t)K + k0 + c8 * 8, &Bs[g * 8][0]);
        }
        __syncthreads();
        #pragma unroll
        for (int s = 0; s < 2; ++s) {
            int coff = ((s * 4 + quad) ^ h8) * 8;   // full 3-bit XOR (r9-verified)
            short8 af[WR], bf[WC];
            #pragma unroll
            for (int i = 0; i < WR; ++i)
                af[i] = *(short8*)&As[wm + i * 16 + l16][coff];
            #pragma unroll
            for (int j = 0; j < WC; ++j)
                bf[j] = *(short8*)&Bs[wn + j * 16 + l16][coff];
            #pragma unroll
            for (int i = 0; i < WR; ++i)
                #pragma unroll
                for (int j = 0; j < WC; ++j)
                    acc[i][j] = __builtin_amdgcn_mfma_f32_16x16x32_bf16(
                        af[i], bf[j], acc[i][j], 0, 0, 0);
        }
    }
    // C/D layout (on-target verified): col = lane&15, row = quad*4 + reg
    #pragma unroll
    for (int i = 0; i < WR; ++i)
        #pragma unroll
        for (int j = 0; j < WC; ++j)
            #pragma unroll
            for (int reg = 0; reg < 4; ++reg) {
                size_t row = row0 + wm + i * 16 + quad * 4 + reg;
                size_t col = col0 + wn + j * 16 + l16;
                float v = acc[i][j][reg];
                if (EPI == 2) v += ((const float*)Rg)[row * (size_t)ldc + col];
                if (EPI == 3) v += bfv(((const u16*)Rg)[row * (size_t)ldc + col]);
                if (EPI == 1) v = fmaxf(v, 0.f);
                if (WF32)  Cf[row * (size_t)ldc + col] = v;
                if (WBF16) Cb[row * (size_t)ldc + col] = f2bf(v);
            }
}

// ============ 4-deep pipelined GEMM (BK=32, counted vmcnt, 2 barriers/tile) =========
// Per K-tile (32): issue 4 gload_lds for tile t+3 into buf[(t+3)&3] (the buffer
// freed at end of iter t-1); s_waitcnt vmcnt(12) = counted wait (12 younger loads
// for tiles t+1..t+3 stay IN FLIGHT; tile t's loads, issued 3 iters (~1200cyc) ago,
// must have landed); barrier (all waves confirmed); ds_read 4..12 b128 frags;
// 16/32 MFMA (setprio-wrapped); barrier (frees buf[t&3]). No vmcnt(0) in the loop.
// Tail handled by uniform dummy loads (source clamped to tile 0, dest = dead buf).
// Swizzle: rows of 4x16B chunks, chunk ^= (r&3)^((r>>2)&3) (<=2-way bank = free).
// sched_barrier(0) pins the 4 sync points (rule #18). Requires K%32==0, K>=128,
// M%TM==0, N%TN==0, gridDim.y%8==0 for XCD remap.
// Geometries: G1 <256,256,2,4> 512thr 128KiB (1 blk/CU); G2 <128,128,2,2> 256thr
// 64KiB (2 blk/CU) for N=512 GEMMs so the grid fills all 256 CUs.
template<int TM, int TN, int WMW, int WNW, int EPI, int WF32, int WBF16>
__global__ __launch_bounds__(WMW * WNW * 64, 2) void gemm_p4(
    const u16* __restrict__ Ab, const u16* __restrict__ Btb,
    float* __restrict__ Cf, u16* __restrict__ Cb, const void* __restrict__ Rg,
    int K, int ldc)
{
    constexpr int NW = WMW * WNW;
    constexpr int FM = TM / WMW / 16;      // A frags per wave
    constexpr int FN = TN / WNW / 16;      // B frags per wave
    constexpr int CA = TM / 16 / NW;       // A staging instrs per wave (=2)
    constexpr int CBn = TN / 16 / NW;      // B staging instrs per wave (=2)
    __shared__ __align__(16) u16 As[4][TM][32];
    __shared__ __align__(16) u16 Bs[4][TN][32];
    int tid = threadIdx.x;
    int lane = tid & 63, wave = tid >> 6;
    int quad = lane >> 4, l16 = lane & 15;
    int wm = (wave / WNW) * (FM * 16);
    int wn = (wave % WNW) * (FN * 16);

    int gx = gridDim.x, gy = gridDim.y;
    int bx, by;
    if ((gy & 7) == 0) {
        int id = blockIdx.y * gx + blockIdx.x;
        int xcd = id & 7, slot = id >> 3;
        bx = slot % gx;
        by = xcd * (gy >> 3) + slot / gx;
    } else {
        bx = blockIdx.x;
        by = blockIdx.y;
    }
    size_t row0 = (size_t)by * TM;
    size_t col0 = (size_t)bx * TN;

    f32x4 acc[FM][FN];
    #pragma unroll
    for (int i = 0; i < FM; ++i)
        #pragma unroll
        for (int j = 0; j < FN; ++j)
            acc[i][j] = (f32x4){0.f, 0.f, 0.f, 0.f};

    // staging: wave covers 16 rows/instr; row r holds source chunk (cl ^ swz(r))
    // at physical chunk cl, swz(r) = (r&3)^((r>>2)&3) for r = row mod 16
    int srow = lane >> 2;
    int swz = (srow & 3) ^ (srow >> 2);
    int sc = (lane & 3) ^ swz;
    size_t aoff[CA], boff[CBn];
    #pragma unroll
    for (int it = 0; it < CA; ++it)
        aoff[it] = (row0 + (size_t)(wave + it * NW) * 16 + srow) * (size_t)K + sc * 8;
    #pragma unroll
    for (int it = 0; it < CBn; ++it)
        boff[it] = (col0 + (size_t)(wave + it * NW) * 16 + srow) * (size_t)K + sc * 8;

    // read swizzle: fragment row = base16 + l16, logical k-chunk = quad
    int gr = (l16 & 3) ^ (l16 >> 2);
    int rc = (quad ^ gr) * 8;              // elem offset of 16B chunk in row

    int nt = K >> 5;
    // prologue: tiles 0,1,2 -> bufs 0,1,2 (12 loads in flight)
    #pragma unroll
    for (int pt = 0; pt < 3; ++pt) {
        size_t ko = (size_t)pt * 32;
        #pragma unroll
        for (int it = 0; it < CA; ++it)
            gload_lds(Ab + aoff[it] + ko, &As[pt][(wave + it * NW) * 16][0]);
        #pragma unroll
        for (int it = 0; it < CBn; ++it)
            gload_lds(Btb + boff[it] + ko, &Bs[pt][(wave + it * NW) * 16][0]);
    }

    #pragma unroll 1
    for (int t = 0; t < nt; ++t) {
        // stage tile t+3 into buf freed at end of iter t-1 (dummy at tail: src
        // clamped to tile 0, dest buffer is never read again -> harmless)
        int db = (t + 3) & 3;
        size_t ko = (size_t)(t + 3 < nt ? t + 3 : 0) * 32;
        #pragma unroll
        for (int it = 0; it < CA; ++it)
            gload_lds(Ab + aoff[it] + ko, &As[db][(wave + it * NW) * 16][0]);
        #pragma unroll
        for (int it = 0; it < CBn; ++it)
            gload_lds(Btb + boff[it] + ko, &Bs[db][(wave + it * NW) * 16][0]);
        __builtin_amdgcn_sched_barrier(0);
        asm volatile("s_waitcnt vmcnt(12)" ::: "memory");   // tile t landed; t+1..t+3 in flight
        __builtin_amdgcn_sched_barrier(0);
        __builtin_amdgcn_s_barrier();                       // all waves confirmed
        __builtin_amdgcn_sched_barrier(0);
        int buf = t & 3;
        short8 af[FM], bf[FN];
        #pragma unroll
        for (int j = 0; j < FN; ++j)
            bf[j] = *(short8*)&Bs[buf][wn + j * 16 + l16][rc];
        #pragma unroll
        for (int i = 0; i < FM; ++i)
            af[i] = *(short8*)&As[buf][wm + i * 16 + l16][rc];
        __builtin_amdgcn_s_setprio(1);
        #pragma unroll
        for (int i = 0; i < FM; ++i)
            #pragma unroll
            for (int j = 0; j < FN; ++j)
                acc[i][j] = __builtin_amdgcn_mfma_f32_16x16x32_bf16(
                    af[i], bf[j], acc[i][j], 0, 0, 0);
        __builtin_amdgcn_s_setprio(0);
        __builtin_amdgcn_sched_barrier(0);                  // reads done before barrier
        __builtin_amdgcn_s_barrier();                       // frees buf[t&3]
    }

    // C/D layout (on-target verified): col = lane&15, row = quad*4 + reg
    #pragma unroll
    for (int i = 0; i < FM; ++i)
        #pragma unroll
        for (int j = 0; j < FN; ++j)
            #pragma unroll
            for (int reg = 0; reg < 4; ++reg) {
                size_t row = row0 + wm + i * 16 + quad * 4 + reg;
                size_t col = col0 + wn + j * 16 + l16;
                float v = acc[i][j][reg];
                if (EPI == 2) v += ((const float*)Rg)[row * (size_t)ldc + col];
                if (EPI == 3) v += bfv(((const u16*)Rg)[row * (size_t)ldc + col]);
                if (EPI == 1) v = fmaxf(v, 0.f);
                if (WF32)  Cf[row * (size_t)ldc + col] = v;
                if (WBF16) Cb[row * (size_t)ldc + col] = f2bf(v);
            }
}

// ============ fused attention per (b,m): all-heads phases, 3 barriers ===============
template<int CTX, int LD>
__global__ __launch_bounds__(256) void attn_fused_kernel(
    const u16* __restrict__ QKVb, const float* __restrict__ maskf, int bm0,
    float* __restrict__ att_sum, u16* __restrict__ ctxb)
{
    __shared__ __align__(16) u16 sQ[16][520];
    __shared__ __align__(16) u16 sK[16][520];
    __shared__ __align__(16) u16 sV[CTX ? 16 : 1][520];
    __shared__ float s_p[H_][16][17];
    int bm_l = blockIdx.x;
    int tid = threadIdx.x;
    int t = tid >> 4, ch = (tid & 15) * 32;
    const u16* base = QKVb + ((size_t)bm_l * T_ + t) * LD;
    #pragma unroll
    for (int c = 0; c < 4; ++c) {
        *(uint4*)&sQ[t][ch + c * 8] = *(const uint4*)(base + ch + c * 8);
        *(uint4*)&sK[t][ch + c * 8] = *(const uint4*)(base + 512 + ch + c * 8);
        if (CTX) *(uint4*)&sV[t][ch + c * 8] = *(const uint4*)(base + 1024 + ch + c * 8);
    }
    __syncthreads();

    int b = (bm0 + bm_l) >> 5;                  // bm = b*NN + m

    #pragma unroll
    for (int r = 0; r < 8; ++r) {
        int h = r;
        int q = (tid >> 4) & 15, k = tid & 15;
        const u32* qu = (const u32*)&sQ[q][0] + h * 32;
        const u32* ku = (const u32*)&sK[k][0] + h * 32;
        float acc = 0.f;
        #pragma unroll
        for (int j = 0; j < 32; ++j) {
            u32 a = qu[j], bb = ku[j];
            acc += bfv((u16)(a & 0xffff)) * bfv((u16)(bb & 0xffff));
            acc += bfv((u16)(a >> 16))    * bfv((u16)(bb >> 16));
        }
        acc *= 0.125f;
        if (maskf[(size_t)(bm0 + bm_l) * T_ + q] == 0.0f) acc = -1e9f;
        s_p[h][q][k] = acc;
    }
    __syncthreads();
    if (tid < 128) {
        int h = tid >> 4, q = tid & 15;
        float mx = -3.4e38f;
        #pragma unroll
        for (int kk = 0; kk < 16; ++kk) mx = fmaxf(mx, s_p[h][q][kk]);
        float e[16], s = 0.f;
        #pragma unroll
        for (int kk = 0; kk < 16; ++kk) { e[kk] = expf(s_p[h][q][kk] - mx); s += e[kk]; }
        float inv = 1.0f / s;
        #pragma unroll
        for (int kk = 0; kk < 16; ++kk) s_p[h][q][kk] = e[kk] * inv;
    }
    __syncthreads();
    #pragma unroll
    for (int r = 0; r < 8; ++r) {
        int h = r;
        int q = (tid >> 4) & 15, k = tid & 15;
        atomicAdd(&att_sum[(((size_t)b * H_ + h) * T_ + q) * T_ + k], s_p[h][q][k]);
    }
    if (CTX) {
        #pragma unroll
        for (int rep = 0; rep < 16; ++rep) {
            int i2 = rep * 256 + tid;           // t*256 + c2, c2 = (h*64+dk)/2
            int tt = i2 >> 8, c2 = i2 & 255;
            int h = c2 >> 5;
            const float* pr = &s_p[h][tt][0];
            float a0 = 0.f, a1 = 0.f;
            #pragma unroll
            for (int kk = 0; kk < 16; ++kk) {
                u32 vv = *((const u32*)&sV[kk][0] + c2);
                float p = pr[kk];
                a0 += p * bfv((u16)(vv & 0xffff));
                a1 += p * bfv((u16)(vv >> 16));
            }
            u32 o = (u32)f2bf(a0) | ((u32)f2bf(a1) << 16);
            *((u32*)(ctxb + ((size_t)bm_l * T_ + tt) * D_) + c2) = o;
        }
    }
}

// ============ fused self-attention + combine + si, one block per (n,h) ==============
__global__ __launch_bounds__(256) void siatt_kernel(
    const float* __restrict__ xemb, const float* __restrict__ att_sum,
    const float* __restrict__ attf, u16* __restrict__ sib)
{
    __shared__ float sX[16][516];
    __shared__ float sS[16][17];
    __shared__ float sA[16][17];
    int n = blockIdx.x >> 3, h = blockIdx.x & 7;
    int tid = threadIdx.x;
    int t = tid >> 4, ch = (tid & 15) * 32;
    const float* src = xemb + ((size_t)n * T_ + t) * D_;
    #pragma unroll
    for (int c = 0; c < 8; ++c)
        *(float4*)&sX[t][ch + c * 4] = *(const float4*)(src + ch + c * 4);
    __syncthreads();
    int q = tid >> 4, k = tid & 15;
    {
        float acc = 0.f;
        for (int d = 0; d < D_; ++d) acc += sX[q][d] * sX[k][d];
        sS[q][k] = acc * 0.04419417382415922f;
    }
    __syncthreads();
    if (tid < T_) {
        float mx = -3.4e38f;
        #pragma unroll
        for (int kk = 0; kk < 16; ++kk) mx = fmaxf(mx, sS[tid][kk]);
        float e[16], s = 0.f;
        #pragma unroll
        for (int kk = 0; kk < 16; ++kk) { e[kk] = expf(sS[tid][kk] - mx); s += e[kk]; }
        float inv = 1.0f / s;
        #pragma unroll
        for (int kk = 0; kk < 16; ++kk) sS[tid][kk] = e[kk] * inv;
    }
    __syncthreads();
    float f = attf[0] * (1.0f / 32.0f);
    sA[q][k] = sS[q][k] + f * att_sum[((size_t)n * H_ + h) * 256 + q * 16 + k];
    __syncthreads();
    #pragma unroll
    for (int rep = 0; rep < 16; ++rep) {
        int i2 = rep * 256 + tid;          // q*256 + d2
        int qq = i2 >> 8, d2 = (i2 & 255) * 2;
        const float* ar = &sA[qq][0];
        float a0 = 0.f, a1 = 0.f;
        #pragma unroll
        for (int tt = 0; tt < 16; ++tt) {
            float p = ar[tt];
            a0 += p * sX[tt][d2];
            a1 += p * sX[tt][d2 + 1];
        }
        u32 o = (u32)f2bf(a0) | ((u32)f2bf(a1) << 16);
        *((u32*)(sib + (size_t)n * T_ * 4096 + (size_t)qq * 4096 + h * 512) + (d2 >> 1)) = o;
    }
}

// ---------------- positional encoding ------------------------------------------------
__global__ void pe_kernel(float* pe) {
    int i = blockIdx.x * blockDim.x + threadIdx.x;
    if (i >= T_ * 256) return;
    int t = i >> 8, j = i & 255;
    float dv = (float)pow(10000.0, (double)j / 256.0);
    float a = (float)t * dv;
    double ad = (double)a;
    pe[t * D_ + 2 * j]     = (float)sin(ad);
    pe[t * D_ + 2 * j + 1] = (float)cos(ad);
}

// ---------------- x features + embed -------------------------------------------------
__global__ void xemb_kernel(const float* x, const float* Wx, const float* bx,
                            const float* pe, float* xemb) {
    int row = blockIdx.x;              // t*N + n
    int t = row / N_, n = row % N_;
    float x0 = x[row * 6 + 0], x1 = x[row * 6 + 1];
    float x2 = x[row * 6 + 2], x3 = x[row * 6 + 3];
    float x4 = x[row * 6 + 4], x5 = x[row * 6 + 5];
    float vel = sqrtf(x2 * x2 + x3 * x3);
    float ang = atanf(x5 / x4);
    float f0 = ntn(x0), f1 = ntn(x1), f2 = ntn(vel), f3 = ntn(ang);
    for (int d = threadIdx.x; d < D_; d += blockDim.x) {
        xemb[((size_t)n * T_ + t) * D_ + d] =
            f0 * Wx[0 * D_ + d] + f1 * Wx[1 * D_ + d]
          + f2 * Wx[2 * D_ + d] + f3 * Wx[3 * D_ + d]
          + bx[d] + pe[t * D_ + d];
    }
}

// ---------------- neighbor features + mask -------------------------------------------
__global__ void nbr_kernel(const float* x, const float* nbr, float* nf, float* maskf) {
    int idx = blockIdx.x * blockDim.x + threadIdx.x;   // t*N*NN + n*NN + m
    if (idx >= T_ * N_ * NN_) return;
    int m = idx % NN_;
    int tn = idx / NN_;
    int n = tn % N_, t = tn / N_;
    float px = x[((size_t)t * N_ + n) * 6 + 0];
    float py = x[((size_t)t * N_ + n) * 6 + 1];
    float vx, vy;
    if (t == 0) {
        vx = x[((size_t)1 * N_ + n) * 6 + 2];
        vy = x[((size_t)1 * N_ + n) * 6 + 3];
    } else {
        vx = px - x[((size_t)(t - 1) * N_ + n) * 6 + 0];
        vy = py - x[((size_t)(t - 1) * N_ + n) * 6 + 1];
    }
    float nx  = nbr[(size_t)idx * 4 + 0], ny  = nbr[(size_t)idx * 4 + 1];
    float nvx = nbr[(size_t)idx * 4 + 2], nvy = nbr[(size_t)idx * 4 + 3];
    float dpx = nx - px, dpy = ny - py;
    float dvx = nvx - vx, dvy = nvy - vy;
    float dist = sqrtf(dpx * dpx + dpy * dpy);
    maskf[((size_t)n * NN_ + m) * T_ + t] = (dist <= 2.0f) ? 1.0f : 0.0f;
    float vn = sqrtf(vx * vx + vy * vy);
    float bearing = (dpx * vx + dpy * vy) / (dist * vn);
    if (isnan(bearing)) bearing = 0.0f;
    float dvn = sqrtf(dvx * dvx + dvy * dvy);
    float tau = -(dpx * dvx + dpy * dvy) / dvn;
    if (isnan(tau)) tau = 0.0f;
    tau = fminf(fmaxf(tau, 0.0f), 7.0f);
    float mx_ = dpx + tau * dvx, my_ = dpy + tau * dvy;
    float mpd = sqrtf(mx_ * mx_ + my_ * my_);
    nf[(size_t)idx * 3 + 0] = ntn(dist);
    nf[(size_t)idx * 3 + 1] = ntn(bearing);
    nf[(size_t)idx * 3 + 2] = ntn(mpd);
}

// ---------------- neighbor embed: bf16 n_emb only ------------------------------------
__global__ void nemb_kernel(const float* nf, const float* Wn, const float* bn,
                            const float* pe, u16* Ab) {
    int row = blockIdx.x;              // (b*NN+m)*T + t
    int t = row % T_;
    int bm = row / T_;
    int m = bm % NN_, b = bm / NN_;
    size_t nfrow = (((size_t)t * N_ + b) * NN_ + m) * 3;
    float f0 = nf[nfrow], f1 = nf[nfrow + 1], f2 = nf[nfrow + 2];
    for (int d = threadIdx.x; d < D_; d += blockDim.x) {
        float v = f0 * Wn[d] + f1 * Wn[D_ + d] + f2 * Wn[2 * D_ + d]
                + bn[d] + pe[t * D_ + d];
        Ab[(size_t)row * D_ + d] = f2bf(v);
    }
}

// ---------------- LayerNorm, one wave per row; input f32 or bf16; dual out -----------
template<int INBF>
__global__ __launch_bounds__(256) void ln_kernel(
    const void* X, const float* g, const float* b, float* outF, u16* outB, int nrows) {
    int row = blockIdx.x * 4 + (threadIdx.x >> 6);
    if (row >= nrows) return;
    int lane = threadIdx.x & 63;
    float v[8];
    float s = 0.f;
    #pragma unroll
    for (int r = 0; r < 8; ++r) {
        int d = lane + r * 64;
        v[r] = INBF ? bfv(((const u16*)X)[(size_t)row * D_ + d])
                    : ((const float*)X)[(size_t)row * D_ + d];
        s += v[r];
    }
    s = wave_sum(s);
    float mean = s * (1.0f / 512.0f);
    float vs = 0.f;
    #pragma unroll
    for (int r = 0; r < 8; ++r) { float d = v[r] - mean; vs += d * d; }
    vs = wave_sum(vs);
    float rstd = rsqrtf(vs * (1.0f / 512.0f) + 1e-5f);
    #pragma unroll
    for (int r = 0; r < 8; ++r) {
        int d = lane + r * 64;
        float o = (v[r] - mean) * rstd * g[d] + b[d];
        if (outF) outF[(size_t)row * D_ + d] = o;
        if (outB) outB[(size_t)row * D_ + d] = f2bf(o);
    }
}

// ---------------- prediction head + broadcast fused (f32 out) ------------------------
__global__ void predbcast_kernel(const float* xemb, const float* Wp, const float* bp,
                                 float* out) {
    int idx = blockIdx.x * blockDim.x + threadIdx.x;   // (n*T+t)*2 + c
    if (idx >= N_ * T_ * 2) return;
    int c = idx & 1;
    int nt = idx >> 1;
    int n = nt / T_, t = nt % T_;
    float acc = bp[c];
    for (int j = 0; j < D_; ++j) acc += xemb[(size_t)nt * D_ + j] * Wp[(size_t)j * 2 + c];
    #pragma unroll
    for (int p = 0; p < NPRED_; ++p)
        out[(((size_t)p * T_ + t) * N_ + n) * 2 + c] = acc;
}

extern "C" void kernel_launch(void* const* d_in, const int* in_sizes, int n_in,
                              void* d_out, int out_size, void* d_ws, size_t ws_size,
                              hipStream_t stream) {
    (void)in_sizes; (void)n_in; (void)out_size; (void)ws_size;

    const float* x    = (const float*)d_in[0];
    const float* nbr  = (const float*)d_in[1];
    const float* attf = (const float*)d_in[2];
    const float* Wx   = (const float*)d_in[3];
    const float* bx   = (const float*)d_in[4];
    const float* Wn   = (const float*)d_in[5];
    const float* bn   = (const float*)d_in[6];
    const float* Wp   = (const float*)d_in[7];
    const float* bp   = (const float*)d_in[8];
    const float* WQ   = (const float*)d_in[9];
    const float* WK   = (const float*)d_in[10];
    const float* WV   = (const float*)d_in[11];
    const float* Wfc  = (const float*)d_in[12];
    const float* mlng = (const float*)d_in[13];
    const float* mlnb = (const float*)d_in[14];
    const float* WSI  = (const float*)d_in[15];
    const float* fsw1 = (const float*)d_in[16];
    const float* fsw2 = (const float*)d_in[17];
    const float* fsg  = (const float*)d_in[18];
    const float* fsb  = (const float*)d_in[19];
    const float* fiw1 = (const float*)d_in[20];
    const float* fiw2 = (const float*)d_in[21];
    const float* fig  = (const float*)d_in[22];
    const float* fib  = (const float*)d_in[23];

    char* w = (char*)d_ws;
    size_t off = 0;
    auto alloc = [&](size_t bytes) -> void* {
        void* p = w + off;
        off = (off + bytes + 255) & ~(size_t)255;
        return p;
    };
    const size_t MiB = 1024 * 1024;

    const int BM = N_ * NN_;          // 2048 (b,m) pairs
    const int ROWS_I = BM * T_;       // 32768 neighbor rows
    const int CB = 1024;              // bm per chunk (NCH=2, l=0 only)
    const int RC = CB * T_;           // 16384 rows per chunk
    const int NCH = ROWS_I / RC;      // 2

    float* pe      = (float*)alloc((size_t)T_ * D_ * 4);
    float* xemb    = (float*)alloc((size_t)N_ * T_ * D_ * 4);
    float* nf      = (float*)alloc((size_t)T_ * N_ * NN_ * 3 * 4);
    float* maskf   = (float*)alloc((size_t)BM * T_ * 4);
    u16*   Ab      = (u16*)alloc((size_t)ROWS_I * D_ * 2);     // n_emb bf16  32 MiB
    u16* tQKV[2], *tWSI[2], *tfs1[2], *tfs2[2];
    for (int l = 0; l < 2; ++l) {
        tQKV[l] = (u16*)alloc((size_t)1536 * 512 * 2);
        tWSI[l] = (u16*)alloc((size_t)512 * 4096 * 2);
        tfs1[l] = (u16*)alloc((size_t)2048 * 512 * 2);
        tfs2[l] = (u16*)alloc((size_t)512 * 2048 * 2);
    }
    u16* tWfc = (u16*)alloc((size_t)512 * 512 * 2);
    u16* tfi1 = (u16*)alloc((size_t)2048 * 512 * 2);
    u16* tfi2 = (u16*)alloc((size_t)512 * 2048 * 2);
    // scratch union: l0 chunk: QKVb 48 + ctxb 16 | hid 64 ; l1: QK full 64 MiB
    char* SCR  = (char*)alloc(64 * MiB);
    u16*   QKVb = (u16*)SCR;
    u16*   ctxb = (u16*)(SCR + 48 * MiB);
    u16*   hid  = (u16*)SCR;
    u16*   BbA    = (u16*)alloc((size_t)RC * D_ * 2);  // pre-LN bf16 chunk    16 MiB
    u16*   Bb_res = (u16*)alloc((size_t)RC * D_ * 2);  // res_inter bf16       16 MiB
    float* att_sum = (float*)alloc((size_t)N_ * H_ * 256 * 4);
    u16*   sib     = (u16*)alloc((size_t)N_ * T_ * 4096 * 2);  // 8 MiB
    float* xnew    = (float*)alloc((size_t)N_ * T_ * D_ * 4);
    u16*   xnb     = (u16*)alloc((size_t)N_ * T_ * D_ * 2);
    // total ~170 MiB

    // ---- batched weight conversion: 14 jobs, one launch ----
    WJobs jobs;
    int ntiles = 0;
    auto addJob = [&](int idx, const float* src, u16* dst, int K, int N) {
        jobs.j[idx] = {src, dst, K, N, ntiles};
        ntiles += (N >> 5) * (K >> 5);
    };
    addJob(0,  WQ,                            tQKV[0],              512, 512);
    addJob(1,  WK,                            tQKV[0] + 512 * 512,  512, 512);
    addJob(2,  WV,                            tQKV[0] + 1024 * 512, 512, 512);   // dead at l=1
    addJob(3,  WQ + (size_t)512 * 512,        tQKV[1],              512, 512);
    addJob(4,  WK + (size_t)512 * 512,        tQKV[1] + 512 * 512,  512, 512);
    addJob(5,  Wfc,                           tWfc,                 512, 512);
    addJob(6,  WSI,                           tWSI[0],              4096, 512);
    addJob(7,  WSI + (size_t)4096 * 512,      tWSI[1],              4096, 512);
    addJob(8,  fsw1,                          tfs1[0],              512, 2048);
    addJob(9,  fsw1 + (size_t)512 * 2048,     tfs1[1],              512, 2048);
    addJob(10, fsw2,                          tfs2[0],              2048, 512);
    addJob(11, fsw2 + (size_t)2048 * 512,     tfs2[1],              2048, 512);
    addJob(12, fiw1,                          tfi1,                 512, 2048);
    addJob(13, fiw2,                          tfi2,                 2048, 512);
    wconv_all<<<ntiles, 256, 0, stream>>>(jobs, ntiles);

    pe_kernel<<<16, 256, 0, stream>>>(pe);
    xemb_kernel<<<T_ * N_, 256, 0, stream>>>(x, Wx, bx, pe, xemb);
    nbr_kernel<<<(T_ * N_ * NN_ + 255) / 256, 256, 0, stream>>>(x, nbr, nf, maskf);
    nemb_kernel<<<BM * T_, 256, 0, stream>>>(nf, Wn, bn, pe, Ab);

    for (int l = 0; l < L_; ++l) {
        hipMemsetAsync(att_sum, 0, (size_t)N_ * H_ * 256 * 4, stream);
        if (l == 0) {
            for (int c = 0; c < NCH; ++c) {
                u16* Acb = Ab + (size_t)c * RC * D_;
                // QKV fused GEMM: N=1536, 256x256 G1 (384 blocks)
                gemm_p4<256, 256, 2, 4, 0, 0, 1><<<dim3(6, RC / 256), 512, 0, stream>>>(
                    Acb, tQKV[0], nullptr, QKVb, nullptr, 512, 1536);
                attn_fused_kernel<1, 1536><<<CB, 256, 0, stream>>>(
                    QKVb, maskf, c * CB, att_sum, ctxb);
                // fc + residual(n_emb bf16) -> pre-LN bf16: 128x128 G2 (512 blocks)
                gemm_p4<128, 128, 2, 2, 3, 0, 1><<<dim3(4, RC / 128), 256, 0, stream>>>(
                    ctxb, tWfc, nullptr, BbA, Acb, 512, 512);
                ln_kernel<1><<<RC / 4, 256, 0, stream>>>(
                    BbA, mlng, mlnb, nullptr, Bb_res, RC);   // res_inter bf16
                // ffi1 relu: N=2048, 256x256 G1 (512 blocks); hid aliases QKVb/ctxb
                gemm_p4<256, 256, 2, 4, 1, 0, 1><<<dim3(8, RC / 256), 512, 0, stream>>>(
                    Bb_res, tfi1, nullptr, hid, nullptr, 512, 2048);
                // ffi2 + residual(res_inter bf16) -> pre-LN bf16: 128x128 G2 (512 blocks)
                gemm_p4<128, 128, 2, 2, 3, 0, 1><<<dim3(4, RC / 128), 256, 0, stream>>>(
                    hid, tfi2, nullptr, BbA, Bb_res, 2048, 512);
                ln_kernel<1><<<RC / 4, 256, 0, stream>>>(
                    BbA, fig, fib, nullptr, Acb, RC);        // new n_emb (bf16)
            }
        } else {
            // l=1: unchunked QK (N=1024, ldc=1024; 64 MiB = SCR) + one attn pass
            gemm_p4<256, 256, 2, 4, 0, 0, 1><<<dim3(4, ROWS_I / 256), 512, 0, stream>>>(
                Ab, tQKV[1], nullptr, QKVb, nullptr, 512, 1024);
            attn_fused_kernel<0, 1024><<<BM, 256, 0, stream>>>(
                QKVb, maskf, 0, att_sum, nullptr);
        }

        // ---- self-attention + si + ffs (updates xemb; f32 chain unchanged) ----
        siatt_kernel<<<N_ * H_, 256, 0, stream>>>(xemb, att_sum, attf, sib);
        gemm_bt<32, 64, 0, 1, 1><<<dim3(8, 32), 256, 0, stream>>>(
            sib, tWSI[l], xnew, xnb, nullptr, 4096, 512);
        gemm_bt<32, 64, 1, 0, 1><<<dim3(32, 32), 256, 0, stream>>>(
            xnb, tfs1[l], nullptr, hid, nullptr, 512, 2048);
        gemm_bt<32, 64, 2, 1, 0><<<dim3(8, 32), 256, 0, stream>>>(
            hid, tfs2[l], xemb, nullptr, xnew, 2048, 512);
        ln_kernel<0><<<(N_ * T_) / 4, 256, 0, stream>>>(
            xemb, fsg + l * D_, fsb + l * D_, xemb, nullptr, N_ * T_);
    }

    predbcast_kernel<<<(N_ * T_ * 2 + 255) / 256, 256, 0, stream>>>(
        xemb, Wp, bp, (float*)d_out);
}

// Round 3
// 840.440 us; speedup vs baseline: 1.0866x; 1.0701x over previous
//
#include <hip/hip_runtime.h>
#include <math.h>

// DTYPE COMMITMENTS (evidence-backed): inputs f32, output f32 (rounds 4-14 PASS).
// WS BUDGET: <= ~210 MB decimal; this build ~170 MiB.

#define T_ 16
#define N_ 64
#define NN_ 32
#define D_ 512
#define H_ 8
#define DK_ 64
#define DFF_ 2048
#define L_ 2
#define NPRED_ 20

typedef unsigned short u16;
typedef unsigned int u32;
typedef __attribute__((ext_vector_type(8))) short short8;
typedef __attribute__((ext_vector_type(4))) float f32x4;

__device__ __forceinline__ u16 f2bf(float f) {
    u32 u = __float_as_uint(f);
    u32 r = u + 0x7fffu + ((u >> 16) & 1u);
    return (u16)(r >> 16);
}
__device__ __forceinline__ float bfv(u16 v) {
    return __uint_as_float(((u32)v) << 16);
}
__device__ __forceinline__ float ntn(float v) {
    if (isnan(v)) return 0.0f;
    if (isinf(v)) return v > 0.0f ? 3.4028234663852886e38f : -3.4028234663852886e38f;
    return v;
}
__device__ __forceinline__ float wave_sum(float v) {
    #pragma unroll
    for (int o = 32; o > 0; o >>= 1) v += __shfl_xor(v, o, 64);
    return v;
}
// async 16B HBM->LDS: writes ldsbase + lane*16 (wave-uniform base, per-lane gptr)
__device__ __forceinline__ void gload_lds(const u16* g, u16* l) {
    __builtin_amdgcn_global_load_lds(
        (const __attribute__((address_space(1))) u32*)g,
        (__attribute__((address_space(3))) u32*)l, 16, 0, 0);
}

// ============ batched weight convert+transpose: 14 jobs in ONE launch ===============
struct WJob { const float* src; u16* dst; int K; int N; int t0; };
struct WJobs { WJob j[14]; };
__global__ __launch_bounds__(256) void wconv_all(WJobs jobs, int ntiles) {
    int bid = blockIdx.x;
    if (bid >= ntiles) return;
    int ji = 0;
    #pragma unroll 1
    for (int i = 1; i < 14; ++i) if (bid >= jobs.j[i].t0) ji = i;
    const float* in = jobs.j[ji].src;
    u16* out = jobs.j[ji].dst;
    int K = jobs.j[ji].K, N = jobs.j[ji].N;
    int lt = bid - jobs.j[ji].t0;
    int ntx = N >> 5;
    int nb = (lt % ntx) * 32, kb = (lt / ntx) * 32;
    __shared__ float tile[32][33];
    int tx = threadIdx.x & 31, ty = threadIdx.x >> 5;
    #pragma unroll
    for (int r = ty; r < 32; r += 8)
        tile[r][tx] = in[(size_t)(kb + r) * N + nb + tx];
    __syncthreads();
    #pragma unroll
    for (int r = ty; r < 32; r += 8)
        out[(size_t)(nb + r) * K + kb + tx] = f2bf(tile[tx][r]);
}

// ============ MFMA GEMM v3 + XCD-band remap (kept for small M=1024 GEMMs) ===========
// DMA staging + 3-bit XOR chunk swizzle (r9: 0 bank conflicts); XCD remap (r10).
// EPI: 0 none, 1 relu, 2 +res f32, 3 +res bf16.
template<int TM, int TN, int EPI, int WF32, int WBF16>
__global__ __launch_bounds__(256) void gemm_bt(
    const u16* __restrict__ Ab, const u16* __restrict__ Btb,
    float* __restrict__ Cf, u16* __restrict__ Cb, const void* __restrict__ Rg,
    int K, int ldc)
{
    constexpr int WR = TM / 32, WC = TN / 32;
    constexpr int ITA = TM / 32, ITB = TN / 32;
    __shared__ __align__(16) u16 As[TM][64];
    __shared__ __align__(16) u16 Bs[TN][64];
    int tid = threadIdx.x;
    int lane = tid & 63, wave = tid >> 6;
    int quad = lane >> 4, l16 = lane & 15;
    int wm = (wave >> 1) * (TM / 2), wn = (wave & 1) * (TN / 2);

    int gx = gridDim.x, gy = gridDim.y;
    int bx, by;
    if ((gy & 7) == 0) {
        int id = blockIdx.y * gx + blockIdx.x;
        int xcd = id & 7;
        int slot = id >> 3;
        bx = slot % gx;
        by = xcd * (gy >> 3) + slot / gx;
    } else {
        bx = blockIdx.x;
        by = blockIdx.y;
    }
    size_t row0 = (size_t)by * TM;
    size_t col0 = (size_t)bx * TN;

    f32x4 acc[WR][WC];
    #pragma unroll
    for (int i = 0; i < WR; ++i)
        #pragma unroll
        for (int j = 0; j < WC; ++j)
            acc[i][j] = (f32x4){0.f, 0.f, 0.f, 0.f};

    int srow = lane >> 3;
    int c8 = (lane & 7) ^ srow;
    int h8 = l16 & 7;

    for (int k0 = 0; k0 < K; k0 += 64) {
        __syncthreads();
        #pragma unroll
        for (int it = 0; it < ITA; ++it) {
            int g = wave + it * 4;
            gload_lds(Ab + (row0 + g * 8 + srow) * (size_t)K + k0 + c8 * 8, &As[g * 8][0]);
        }
        #pragma unroll
        for (int it = 0; it < ITB; ++it) {
            int g = wave + it * 4;
            gload_lds(Btb + (col0 + g * 8 + srow) * (size_t)K + k0 + c8 * 8, &Bs[g * 8][0]);
        }
        __syncthreads();
        #pragma unroll
        for (int s = 0; s < 2; ++s) {
            int coff = ((s * 4 + quad) ^ h8) * 8;   // full 3-bit XOR (r9-verified)
            short8 af[WR], bf[WC];
            #pragma unroll
            for (int i = 0; i < WR; ++i)
                af[i] = *(short8*)&As[wm + i * 16 + l16][coff];
            #pragma unroll
            for (int j = 0; j < WC; ++j)
                bf[j] = *(short8*)&Bs[wn + j * 16 + l16][coff];
            #pragma unroll
            for (int i = 0; i < WR; ++i)
                #pragma unroll
                for (int j = 0; j < WC; ++j)
                    acc[i][j] = __builtin_amdgcn_mfma_f32_16x16x32_bf16(
                        af[i], bf[j], acc[i][j], 0, 0, 0);
        }
    }
    // C/D layout (on-target verified): col = lane&15, row = quad*4 + reg
    #pragma unroll
    for (int i = 0; i < WR; ++i)
        #pragma unroll
        for (int j = 0; j < WC; ++j)
            #pragma unroll
            for (int reg = 0; reg < 4; ++reg) {
                size_t row = row0 + wm + i * 16 + quad * 4 + reg;
                size_t col = col0 + wn + j * 16 + l16;
                float v = acc[i][j][reg];
                if (EPI == 2) v += ((const float*)Rg)[row * (size_t)ldc + col];
                if (EPI == 3) v += bfv(((const u16*)Rg)[row * (size_t)ldc + col]);
                if (EPI == 1) v = fmaxf(v, 0.f);
                if (WF32)  Cf[row * (size_t)ldc + col] = v;
                if (WBF16) Cb[row * (size_t)ldc + col] = f2bf(v);
            }
}

// ============ phase-split double-buffered GEMM (BK=64, burst prefetch) ==============
// Per K-tile: burst-issue all 8 gload_lds for tile t+1 -> other LDS buffer, then
// 2*MH phases of {ds_read 4-8 b128 ; s_barrier ; setprio(1) 16 MFMA setprio(0) ;
// s_barrier}. Wave issues next phase's ds_reads while its own MFMAs drain in the
// pipe (the m196 interleave). Boundary: vmcnt(0) over loads aged ~4 phases (~600cyc,
// covers L2/LLC-hot operands) then barrier -> per-wave drain + rendezvous = all
// staging globally visible (race-free). LDS rows = 128B with the r9-verified 3-bit
// XOR chunk swizzle (0 bank conflicts measured rounds 0-2). Pacing barriers carry
// no data semantics; the only correctness syncs are prologue/boundary vmcnt+barrier.
// G1 <256,256,2,4>: 512thr, 128KiB, 1 blk/CU. G2 <128,128,2,2>: 256thr, 64KiB,
// 2 blk/CU (full chip at 512 WGs for N=512 GEMMs).
// Requires M%TM==0, N%TN==0, K%64==0, gridDim.y%8==0 for XCD remap.
template<int TM, int TN, int WMW, int WNW, int EPI, int WF32, int WBF16>
__global__ __launch_bounds__(WMW * WNW * 64, 2) void gemm_pp(
    const u16* __restrict__ Ab, const u16* __restrict__ Btb,
    float* __restrict__ Cf, u16* __restrict__ Cb, const void* __restrict__ Rg,
    int K, int ldc)
{
    constexpr int NW = WMW * WNW;
    constexpr int FM = TM / WMW / 16;       // G1: 8, G2: 4
    constexpr int FN = TN / WNW / 16;       // 4
    constexpr int MH = (FM * FN > 16) ? 2 : 1;
    constexpr int FMp = FM / MH;            // 4
    constexpr int GA = TM / 8 / NW;         // gloads A per wave per tile (=4)
    constexpr int GB = TN / 8 / NW;         // gloads B per wave per tile (=4)
    __shared__ __align__(16) u16 As[2][TM][64];
    __shared__ __align__(16) u16 Bs[2][TN][64];
    int tid = threadIdx.x;
    int lane = tid & 63, wave = tid >> 6;
    int quad = lane >> 4, l16 = lane & 15;
    int wm = (wave / WNW) * (FM * 16);
    int wn = (wave % WNW) * (FN * 16);

    int gx = gridDim.x, gy = gridDim.y;
    int bx, by;
    {
        int id = blockIdx.y * gx + blockIdx.x;
        int xcd = id & 7, slot = id >> 3;
        bx = slot % gx;
        by = xcd * (gy >> 3) + slot / gx;
    }
    size_t row0 = (size_t)by * TM;
    size_t col0 = (size_t)bx * TN;

    f32x4 acc[FM][FN];
    #pragma unroll
    for (int i = 0; i < FM; ++i)
        #pragma unroll
        for (int j = 0; j < FN; ++j)
            acc[i][j] = (f32x4){0.f, 0.f, 0.f, 0.f};

    // staging swizzle (r9-verified, 0 conflicts): physical 16B chunk p of row r
    // holds logical chunk p ^ (r&7)
    int srow = lane >> 3;
    int c8 = (lane & 7) ^ srow;
    int h8 = l16 & 7;
    size_t aoff[GA], boff[GB];
    #pragma unroll
    for (int it = 0; it < GA; ++it)
        aoff[it] = (row0 + (size_t)(wave + it * NW) * 8 + srow) * (size_t)K + c8 * 8;
    #pragma unroll
    for (int it = 0; it < GB; ++it)
        boff[it] = (col0 + (size_t)(wave + it * NW) * 8 + srow) * (size_t)K + c8 * 8;

    int nt = K >> 6;
    // prologue: stage tile 0 -> buf 0, drain, converge
    #pragma unroll
    for (int it = 0; it < GA; ++it)
        gload_lds(Ab + aoff[it], &As[0][(wave + it * NW) * 8][0]);
    #pragma unroll
    for (int it = 0; it < GB; ++it)
        gload_lds(Btb + boff[it], &Bs[0][(wave + it * NW) * 8][0]);
    asm volatile("s_waitcnt vmcnt(0)" ::: "memory");
    __builtin_amdgcn_s_barrier();

    #pragma unroll 1
    for (int t = 0; t < nt; ++t) {
        int cur = t & 1;
        if (t + 1 < nt) {
            // burst prefetch of tile t+1 into other buffer (aged ~4 phases by the
            // boundary vmcnt(0))
            size_t ko = (size_t)(t + 1) * 64;
            #pragma unroll
            for (int it = 0; it < GA; ++it)
                gload_lds(Ab + aoff[it] + ko, &As[cur ^ 1][(wave + it * NW) * 8][0]);
            #pragma unroll
            for (int it = 0; it < GB; ++it)
                gload_lds(Btb + boff[it] + ko, &Bs[cur ^ 1][(wave + it * NW) * 8][0]);
        }
        short8 bf[FN];
        #pragma unroll
        for (int kh = 0; kh < 2; ++kh) {
            #pragma unroll
            for (int mh = 0; mh < MH; ++mh) {
                int coff = ((kh * 4 + quad) ^ h8) * 8;
                short8 af[FMp];
                if (mh == 0) {
                    #pragma unroll
                    for (int j = 0; j < FN; ++j)
                        bf[j] = *(short8*)&Bs[cur][wn + j * 16 + l16][coff];
                }
                #pragma unroll
                for (int i = 0; i < FMp; ++i)
                    af[i] = *(short8*)&As[cur][wm + (mh * FMp + i) * 16 + l16][coff];
                __builtin_amdgcn_s_barrier();          // phase entry (pacing)
                __builtin_amdgcn_s_setprio(1);
                #pragma unroll
                for (int i = 0; i < FMp; ++i)
                    #pragma unroll
                    for (int j = 0; j < FN; ++j)
                        acc[mh * FMp + i][j] = __builtin_amdgcn_mfma_f32_16x16x32_bf16(
                            af[i], bf[j], acc[mh * FMp + i][j], 0, 0, 0);
                __builtin_amdgcn_s_setprio(0);
                __builtin_amdgcn_s_barrier();          // phase exit (pacing)
            }
        }
        // boundary: own loads drained, then rendezvous -> buf cur^1 fully staged
        if (t + 1 < nt)
            asm volatile("s_waitcnt vmcnt(0)" ::: "memory");
        __builtin_amdgcn_s_barrier();
    }

    // C/D layout (on-target verified): col = lane&15, row = quad*4 + reg
    #pragma unroll
    for (int i = 0; i < FM; ++i)
        #pragma unroll
        for (int j = 0; j < FN; ++j)
            #pragma unroll
            for (int reg = 0; reg < 4; ++reg) {
                size_t row = row0 + wm + i * 16 + quad * 4 + reg;
                size_t col = col0 + wn + j * 16 + l16;
                float v = acc[i][j][reg];
                if (EPI == 2) v += ((const float*)Rg)[row * (size_t)ldc + col];
                if (EPI == 3) v += bfv(((const u16*)Rg)[row * (size_t)ldc + col]);
                if (EPI == 1) v = fmaxf(v, 0.f);
                if (WF32)  Cf[row * (size_t)ldc + col] = v;
                if (WBF16) Cb[row * (size_t)ldc + col] = f2bf(v);
            }
}

// ============ fused attention per (b,m): all-heads phases, 3 barriers ===============
template<int CTX, int LD>
__global__ __launch_bounds__(256) void attn_fused_kernel(
    const u16* __restrict__ QKVb, const float* __restrict__ maskf, int bm0,
    float* __restrict__ att_sum, u16* __restrict__ ctxb)
{
    __shared__ __align__(16) u16 sQ[16][520];
    __shared__ __align__(16) u16 sK[16][520];
    __shared__ __align__(16) u16 sV[CTX ? 16 : 1][520];
    __shared__ float s_p[H_][16][17];
    int bm_l = blockIdx.x;
    int tid = threadIdx.x;
    int t = tid >> 4, ch = (tid & 15) * 32;
    const u16* base = QKVb + ((size_t)bm_l * T_ + t) * LD;
    #pragma unroll
    for (int c = 0; c < 4; ++c) {
        *(uint4*)&sQ[t][ch + c * 8] = *(const uint4*)(base + ch + c * 8);
        *(uint4*)&sK[t][ch + c * 8] = *(const uint4*)(base + 512 + ch + c * 8);
        if (CTX) *(uint4*)&sV[t][ch + c * 8] = *(const uint4*)(base + 1024 + ch + c * 8);
    }
    __syncthreads();

    int b = (bm0 + bm_l) >> 5;                  // bm = b*NN + m

    #pragma unroll
    for (int r = 0; r < 8; ++r) {
        int h = r;
        int q = (tid >> 4) & 15, k = tid & 15;
        const u32* qu = (const u32*)&sQ[q][0] + h * 32;
        const u32* ku = (const u32*)&sK[k][0] + h * 32;
        float acc = 0.f;
        #pragma unroll
        for (int j = 0; j < 32; ++j) {
            u32 a = qu[j], bb = ku[j];
            acc += bfv((u16)(a & 0xffff)) * bfv((u16)(bb & 0xffff));
            acc += bfv((u16)(a >> 16))    * bfv((u16)(bb >> 16));
        }
        acc *= 0.125f;
        if (maskf[(size_t)(bm0 + bm_l) * T_ + q] == 0.0f) acc = -1e9f;
        s_p[h][q][k] = acc;
    }
    __syncthreads();
    if (tid < 128) {
        int h = tid >> 4, q = tid & 15;
        float mx = -3.4e38f;
        #pragma unroll
        for (int kk = 0; kk < 16; ++kk) mx = fmaxf(mx, s_p[h][q][kk]);
        float e[16], s = 0.f;
        #pragma unroll
        for (int kk = 0; kk < 16; ++kk) { e[kk] = expf(s_p[h][q][kk] - mx); s += e[kk]; }
        float inv = 1.0f / s;
        #pragma unroll
        for (int kk = 0; kk < 16; ++kk) s_p[h][q][kk] = e[kk] * inv;
    }
    __syncthreads();
    #pragma unroll
    for (int r = 0; r < 8; ++r) {
        int h = r;
        int q = (tid >> 4) & 15, k = tid & 15;
        atomicAdd(&att_sum[(((size_t)b * H_ + h) * T_ + q) * T_ + k], s_p[h][q][k]);
    }
    if (CTX) {
        #pragma unroll
        for (int rep = 0; rep < 16; ++rep) {
            int i2 = rep * 256 + tid;           // t*256 + c2, c2 = (h*64+dk)/2
            int tt = i2 >> 8, c2 = i2 & 255;
            int h = c2 >> 5;
            const float* pr = &s_p[h][tt][0];
            float a0 = 0.f, a1 = 0.f;
            #pragma unroll
            for (int kk = 0; kk < 16; ++kk) {
                u32 vv = *((const u32*)&sV[kk][0] + c2);
                float p = pr[kk];
                a0 += p * bfv((u16)(vv & 0xffff));
                a1 += p * bfv((u16)(vv >> 16));
            }
            u32 o = (u32)f2bf(a0) | ((u32)f2bf(a1) << 16);
            *((u32*)(ctxb + ((size_t)bm_l * T_ + tt) * D_) + c2) = o;
        }
    }
}

// ============ fused self-attention + combine + si, one block per (n,h) ==============
__global__ __launch_bounds__(256) void siatt_kernel(
    const float* __restrict__ xemb, const float* __restrict__ att_sum,
    const float* __restrict__ attf, u16* __restrict__ sib)
{
    __shared__ float sX[16][516];
    __shared__ float sS[16][17];
    __shared__ float sA[16][17];
    int n = blockIdx.x >> 3, h = blockIdx.x & 7;
    int tid = threadIdx.x;
    int t = tid >> 4, ch = (tid & 15) * 32;
    const float* src = xemb + ((size_t)n * T_ + t) * D_;
    #pragma unroll
    for (int c = 0; c < 8; ++c)
        *(float4*)&sX[t][ch + c * 4] = *(const float4*)(src + ch + c * 4);
    __syncthreads();
    int q = tid >> 4, k = tid & 15;
    {
        float acc = 0.f;
        for (int d = 0; d < D_; ++d) acc += sX[q][d] * sX[k][d];
        sS[q][k] = acc * 0.04419417382415922f;
    }
    __syncthreads();
    if (tid < T_) {
        float mx = -3.4e38f;
        #pragma unroll
        for (int kk = 0; kk < 16; ++kk) mx = fmaxf(mx, sS[tid][kk]);
        float e[16], s = 0.f;
        #pragma unroll
        for (int kk = 0; kk < 16; ++kk) { e[kk] = expf(sS[tid][kk] - mx); s += e[kk]; }
        float inv = 1.0f / s;
        #pragma unroll
        for (int kk = 0; kk < 16; ++kk) sS[tid][kk] = e[kk] * inv;
    }
    __syncthreads();
    float f = attf[0] * (1.0f / 32.0f);
    sA[q][k] = sS[q][k] + f * att_sum[((size_t)n * H_ + h) * 256 + q * 16 + k];
    __syncthreads();
    #pragma unroll
    for (int rep = 0; rep < 16; ++rep) {
        int i2 = rep * 256 + tid;          // q*256 + d2
        int qq = i2 >> 8, d2 = (i2 & 255) * 2;
        const float* ar = &sA[qq][0];
        float a0 = 0.f, a1 = 0.f;
        #pragma unroll
        for (int tt = 0; tt < 16; ++tt) {
            float p = ar[tt];
            a0 += p * sX[tt][d2];
            a1 += p * sX[tt][d2 + 1];
        }
        u32 o = (u32)f2bf(a0) | ((u32)f2bf(a1) << 16);
        *((u32*)(sib + (size_t)n * T_ * 4096 + (size_t)qq * 4096 + h * 512) + (d2 >> 1)) = o;
    }
}

// ---------------- positional encoding ------------------------------------------------
__global__ void pe_kernel(float* pe) {
    int i = blockIdx.x * blockDim.x + threadIdx.x;
    if (i >= T_ * 256) return;
    int t = i >> 8, j = i & 255;
    float dv = (float)pow(10000.0, (double)j / 256.0);
    float a = (float)t * dv;
    double ad = (double)a;
    pe[t * D_ + 2 * j]     = (float)sin(ad);
    pe[t * D_ + 2 * j + 1] = (float)cos(ad);
}

// ---------------- x features + embed -------------------------------------------------
__global__ void xemb_kernel(const float* x, const float* Wx, const float* bx,
                            const float* pe, float* xemb) {
    int row = blockIdx.x;              // t*N + n
    int t = row / N_, n = row % N_;
    float x0 = x[row * 6 + 0], x1 = x[row * 6 + 1];
    float x2 = x[row * 6 + 2], x3 = x[row * 6 + 3];
    float x4 = x[row * 6 + 4], x5 = x[row * 6 + 5];
    float vel = sqrtf(x2 * x2 + x3 * x3);
    float ang = atanf(x5 / x4);
    float f0 = ntn(x0), f1 = ntn(x1), f2 = ntn(vel), f3 = ntn(ang);
    for (int d = threadIdx.x; d < D_; d += blockDim.x) {
        xemb[((size_t)n * T_ + t) * D_ + d] =
            f0 * Wx[0 * D_ + d] + f1 * Wx[1 * D_ + d]
          + f2 * Wx[2 * D_ + d] + f3 * Wx[3 * D_ + d]
          + bx[d] + pe[t * D_ + d];
    }
}

// ---------------- neighbor features + mask -------------------------------------------
__global__ void nbr_kernel(const float* x, const float* nbr, float* nf, float* maskf) {
    int idx = blockIdx.x * blockDim.x + threadIdx.x;   // t*N*NN + n*NN + m
    if (idx >= T_ * N_ * NN_) return;
    int m = idx % NN_;
    int tn = idx / NN_;
    int n = tn % N_, t = tn / N_;
    float px = x[((size_t)t * N_ + n) * 6 + 0];
    float py = x[((size_t)t * N_ + n) * 6 + 1];
    float vx, vy;
    if (t == 0) {
        vx = x[((size_t)1 * N_ + n) * 6 + 2];
        vy = x[((size_t)1 * N_ + n) * 6 + 3];
    } else {
        vx = px - x[((size_t)(t - 1) * N_ + n) * 6 + 0];
        vy = py - x[((size_t)(t - 1) * N_ + n) * 6 + 1];
    }
    float nx  = nbr[(size_t)idx * 4 + 0], ny  = nbr[(size_t)idx * 4 + 1];
    float nvx = nbr[(size_t)idx * 4 + 2], nvy = nbr[(size_t)idx * 4 + 3];
    float dpx = nx - px, dpy = ny - py;
    float dvx = nvx - vx, dvy = nvy - vy;
    float dist = sqrtf(dpx * dpx + dpy * dpy);
    maskf[((size_t)n * NN_ + m) * T_ + t] = (dist <= 2.0f) ? 1.0f : 0.0f;
    float vn = sqrtf(vx * vx + vy * vy);
    float bearing = (dpx * vx + dpy * vy) / (dist * vn);
    if (isnan(bearing)) bearing = 0.0f;
    float dvn = sqrtf(dvx * dvx + dvy * dvy);
    float tau = -(dpx * dvx + dpy * dvy) / dvn;
    if (isnan(tau)) tau = 0.0f;
    tau = fminf(fmaxf(tau, 0.0f), 7.0f);
    float mx_ = dpx + tau * dvx, my_ = dpy + tau * dvy;
    float mpd = sqrtf(mx_ * mx_ + my_ * my_);
    nf[(size_t)idx * 3 + 0] = ntn(dist);
    nf[(size_t)idx * 3 + 1] = ntn(bearing);
    nf[(size_t)idx * 3 + 2] = ntn(mpd);
}

// ---------------- neighbor embed: bf16 n_emb only ------------------------------------
__global__ void nemb_kernel(const float* nf, const float* Wn, const float* bn,
                            const float* pe, u16* Ab) {
    int row = blockIdx.x;              // (b*NN+m)*T + t
    int t = row % T_;
    int bm = row / T_;
    int m = bm % NN_, b = bm / NN_;
    size_t nfrow = (((size_t)t * N_ + b) * NN_ + m) * 3;
    float f0 = nf[nfrow], f1 = nf[nfrow + 1], f2 = nf[nfrow + 2];
    for (int d = threadIdx.x; d < D_; d += blockDim.x) {
        float v = f0 * Wn[d] + f1 * Wn[D_ + d] + f2 * Wn[2 * D_ + d]
                + bn[d] + pe[t * D_ + d];
        Ab[(size_t)row * D_ + d] = f2bf(v);
    }
}

// ---------------- LayerNorm, one wave per row; input f32 or bf16; dual out -----------
template<int INBF>
__global__ __launch_bounds__(256) void ln_kernel(
    const void* X, const float* g, const float* b, float* outF, u16* outB, int nrows) {
    int row = blockIdx.x * 4 + (threadIdx.x >> 6);
    if (row >= nrows) return;
    int lane = threadIdx.x & 63;
    float v[8];
    float s = 0.f;
    #pragma unroll
    for (int r = 0; r < 8; ++r) {
        int d = lane + r * 64;
        v[r] = INBF ? bfv(((const u16*)X)[(size_t)row * D_ + d])
                    : ((const float*)X)[(size_t)row * D_ + d];
        s += v[r];
    }
    s = wave_sum(s);
    float mean = s * (1.0f / 512.0f);
    float vs = 0.f;
    #pragma unroll
    for (int r = 0; r < 8; ++r) { float d = v[r] - mean; vs += d * d; }
    vs = wave_sum(vs);
    float rstd = rsqrtf(vs * (1.0f / 512.0f) + 1e-5f);
    #pragma unroll
    for (int r = 0; r < 8; ++r) {
        int d = lane + r * 64;
        float o = (v[r] - mean) * rstd * g[d] + b[d];
        if (outF) outF[(size_t)row * D_ + d] = o;
        if (outB) outB[(size_t)row * D_ + d] = f2bf(o);
    }
}

// ---------------- prediction head + broadcast fused (f32 out) ------------------------
__global__ void predbcast_kernel(const float* xemb, const float* Wp, const float* bp,
                                 float* out) {
    int idx = blockIdx.x * blockDim.x + threadIdx.x;   // (n*T+t)*2 + c
    if (idx >= N_ * T_ * 2) return;
    int c = idx & 1;
    int nt = idx >> 1;
    int n = nt / T_, t = nt % T_;
    float acc = bp[c];
    for (int j = 0; j < D_; ++j) acc += xemb[(size_t)nt * D_ + j] * Wp[(size_t)j * 2 + c];
    #pragma unroll
    for (int p = 0; p < NPRED_; ++p)
        out[(((size_t)p * T_ + t) * N_ + n) * 2 + c] = acc;
}

extern "C" void kernel_launch(void* const* d_in, const int* in_sizes, int n_in,
                              void* d_out, int out_size, void* d_ws, size_t ws_size,
                              hipStream_t stream) {
    (void)in_sizes; (void)n_in; (void)out_size; (void)ws_size;

    const float* x    = (const float*)d_in[0];
    const float* nbr  = (const float*)d_in[1];
    const float* attf = (const float*)d_in[2];
    const float* Wx   = (const float*)d_in[3];
    const float* bx   = (const float*)d_in[4];
    const float* Wn   = (const float*)d_in[5];
    const float* bn   = (const float*)d_in[6];
    const float* Wp   = (const float*)d_in[7];
    const float* bp   = (const float*)d_in[8];
    const float* WQ   = (const float*)d_in[9];
    const float* WK   = (const float*)d_in[10];
    const float* WV   = (const float*)d_in[11];
    const float* Wfc  = (const float*)d_in[12];
    const float* mlng = (const float*)d_in[13];
    const float* mlnb = (const float*)d_in[14];
    const float* WSI  = (const float*)d_in[15];
    const float* fsw1 = (const float*)d_in[16];
    const float* fsw2 = (const float*)d_in[17];
    const float* fsg  = (const float*)d_in[18];
    const float* fsb  = (const float*)d_in[19];
    const float* fiw1 = (const float*)d_in[20];
    const float* fiw2 = (const float*)d_in[21];
    const float* fig  = (const float*)d_in[22];
    const float* fib  = (const float*)d_in[23];

    char* w = (char*)d_ws;
    size_t off = 0;
    auto alloc = [&](size_t bytes) -> void* {
        void* p = w + off;
        off = (off + bytes + 255) & ~(size_t)255;
        return p;
    };
    const size_t MiB = 1024 * 1024;

    const int BM = N_ * NN_;          // 2048 (b,m) pairs
    const int ROWS_I = BM * T_;       // 32768 neighbor rows
    const int CB = 1024;              // bm per chunk (NCH=2, l=0 only)
    const int RC = CB * T_;           // 16384 rows per chunk
    const int NCH = ROWS_I / RC;      // 2

    float* pe      = (float*)alloc((size_t)T_ * D_ * 4);
    float* xemb    = (float*)alloc((size_t)N_ * T_ * D_ * 4);
    float* nf      = (float*)alloc((size_t)T_ * N_ * NN_ * 3 * 4);
    float* maskf   = (float*)alloc((size_t)BM * T_ * 4);
    u16*   Ab      = (u16*)alloc((size_t)ROWS_I * D_ * 2);     // n_emb bf16  32 MiB
    u16* tQKV[2], *tWSI[2], *tfs1[2], *tfs2[2];
    for (int l = 0; l < 2; ++l) {
        tQKV[l] = (u16*)alloc((size_t)1536 * 512 * 2);
        tWSI[l] = (u16*)alloc((size_t)512 * 4096 * 2);
        tfs1[l] = (u16*)alloc((size_t)2048 * 512 * 2);
        tfs2[l] = (u16*)alloc((size_t)512 * 2048 * 2);
    }
    u16* tWfc = (u16*)alloc((size_t)512 * 512 * 2);
    u16* tfi1 = (u16*)alloc((size_t)2048 * 512 * 2);
    u16* tfi2 = (u16*)alloc((size_t)512 * 2048 * 2);
    // scratch union: l0 chunk: QKVb 48 + ctxb 16 | hid 64 ; l1: QK full 64 MiB
    char* SCR  = (char*)alloc(64 * MiB);
    u16*   QKVb = (u16*)SCR;
    u16*   ctxb = (u16*)(SCR + 48 * MiB);
    u16*   hid  = (u16*)SCR;
    u16*   BbA    = (u16*)alloc((size_t)RC * D_ * 2);  // pre-LN bf16 chunk    16 MiB
    u16*   Bb_res = (u16*)alloc((size_t)RC * D_ * 2);  // res_inter bf16       16 MiB
    float* att_sum = (float*)alloc((size_t)N_ * H_ * 256 * 4);
    u16*   sib     = (u16*)alloc((size_t)N_ * T_ * 4096 * 2);  // 8 MiB
    float* xnew    = (float*)alloc((size_t)N_ * T_ * D_ * 4);
    u16*   xnb     = (u16*)alloc((size_t)N_ * T_ * D_ * 2);
    // total ~170 MiB

    // ---- batched weight conversion: 14 jobs, one launch ----
    WJobs jobs;
    int ntiles = 0;
    auto addJob = [&](int idx, const float* src, u16* dst, int K, int N) {
        jobs.j[idx] = {src, dst, K, N, ntiles};
        ntiles += (N >> 5) * (K >> 5);
    };
    addJob(0,  WQ,                            tQKV[0],              512, 512);
    addJob(1,  WK,                            tQKV[0] + 512 * 512,  512, 512);
    addJob(2,  WV,                            tQKV[0] + 1024 * 512, 512, 512);   // dead at l=1
    addJob(3,  WQ + (size_t)512 * 512,        tQKV[1],              512, 512);
    addJob(4,  WK + (size_t)512 * 512,        tQKV[1] + 512 * 512,  512, 512);
    addJob(5,  Wfc,                           tWfc,                 512, 512);
    addJob(6,  WSI,                           tWSI[0],              4096, 512);
    addJob(7,  WSI + (size_t)4096 * 512,      tWSI[1],              4096, 512);
    addJob(8,  fsw1,                          tfs1[0],              512, 2048);
    addJob(9,  fsw1 + (size_t)512 * 2048,     tfs1[1],              512, 2048);
    addJob(10, fsw2,                          tfs2[0],              2048, 512);
    addJob(11, fsw2 + (size_t)2048 * 512,     tfs2[1],              2048, 512);
    addJob(12, fiw1,                          tfi1,                 512, 2048);
    addJob(13, fiw2,                          tfi2,                 2048, 512);
    wconv_all<<<ntiles, 256, 0, stream>>>(jobs, ntiles);

    pe_kernel<<<16, 256, 0, stream>>>(pe);
    xemb_kernel<<<T_ * N_, 256, 0, stream>>>(x, Wx, bx, pe, xemb);
    nbr_kernel<<<(T_ * N_ * NN_ + 255) / 256, 256, 0, stream>>>(x, nbr, nf, maskf);
    nemb_kernel<<<BM * T_, 256, 0, stream>>>(nf, Wn, bn, pe, Ab);

    for (int l = 0; l < L_; ++l) {
        hipMemsetAsync(att_sum, 0, (size_t)N_ * H_ * 256 * 4, stream);
        if (l == 0) {
            for (int c = 0; c < NCH; ++c) {
                u16* Acb = Ab + (size_t)c * RC * D_;
                // QKV fused GEMM: N=1536, G2 128x128 (1536 blocks = 3 exact rounds)
                gemm_pp<128, 128, 2, 2, 0, 0, 1><<<dim3(12, RC / 128), 256, 0, stream>>>(
                    Acb, tQKV[0], nullptr, QKVb, nullptr, 512, 1536);
                attn_fused_kernel<1, 1536><<<CB, 256, 0, stream>>>(
                    QKVb, maskf, c * CB, att_sum, ctxb);
                // fc + residual(n_emb bf16) -> pre-LN bf16: G2 (512 blocks, full chip)
                gemm_pp<128, 128, 2, 2, 3, 0, 1><<<dim3(4, RC / 128), 256, 0, stream>>>(
                    ctxb, tWfc, nullptr, BbA, Acb, 512, 512);
                ln_kernel<1><<<RC / 4, 256, 0, stream>>>(
                    BbA, mlng, mlnb, nullptr, Bb_res, RC);   // res_inter bf16
                // ffi1 relu: N=2048, G1 256x256 (512 blocks = 2 exact rounds)
                gemm_pp<256, 256, 2, 4, 1, 0, 1><<<dim3(8, RC / 256), 512, 0, stream>>>(
                    Bb_res, tfi1, nullptr, hid, nullptr, 512, 2048);
                // ffi2 + residual(res_inter bf16) -> pre-LN bf16: G2 (512 blocks)
                gemm_pp<128, 128, 2, 2, 3, 0, 1><<<dim3(4, RC / 128), 256, 0, stream>>>(
                    hid, tfi2, nullptr, BbA, Bb_res, 2048, 512);
                ln_kernel<1><<<RC / 4, 256, 0, stream>>>(
                    BbA, fig, fib, nullptr, Acb, RC);        // new n_emb (bf16)
            }
        } else {
            // l=1: unchunked QK (N=1024, ldc=1024; 64 MiB = SCR): G1 (512 blocks)
            gemm_pp<256, 256, 2, 4, 0, 0, 1><<<dim3(4, ROWS_I / 256), 512, 0, stream>>>(
                Ab, tQKV[1], nullptr, QKVb, nullptr, 512, 1024);
            attn_fused_kernel<0, 1024><<<BM, 256, 0, stream>>>(
                QKVb, maskf, 0, att_sum, nullptr);
        }

        // ---- self-attention + si + ffs (updates xemb; f32 chain unchanged) ----
        siatt_kernel<<<N_ * H_, 256, 0, stream>>>(xemb, att_sum, attf, sib);
        gemm_bt<32, 64, 0, 1, 1><<<dim3(8, 32), 256, 0, stream>>>(
            sib, tWSI[l], xnew, xnb, nullptr, 4096, 512);
        gemm_bt<32, 64, 1, 0, 1><<<dim3(32, 32), 256, 0, stream>>>(
            xnb, tfs1[l], nullptr, hid, nullptr, 512, 2048);
        gemm_bt<32, 64, 2, 1, 0><<<dim3(8, 32), 256, 0, stream>>>(
            hid, tfs2[l], xemb, nullptr, xnew, 2048, 512);
        ln_kernel<0><<<(N_ * T_) / 4, 256, 0, stream>>>(
            xemb, fsg + l * D_, fsb + l * D_, xemb, nullptr, N_ * T_);
    }

    predbcast_kernel<<<(N_ * T_ * 2 + 255) / 256, 256, 0, stream>>>(
        xemb, Wp, bp, (float*)d_out);
}

// Round 4
// 813.739 us; speedup vs baseline: 1.1222x; 1.0328x over previous
//
#include <hip/hip_runtime.h>
#include <math.h>

// DTYPE COMMITMENTS (evidence-backed): inputs f32, output f32 (rounds 4-14 PASS).
// WS BUDGET: <= ~210 MB decimal; this build ~170 MiB.

#define T_ 16
#define N_ 64
#define NN_ 32
#define D_ 512
#define H_ 8
#define DK_ 64
#define DFF_ 2048
#define L_ 2
#define NPRED_ 20

typedef unsigned short u16;
typedef unsigned int u32;
typedef __attribute__((ext_vector_type(8))) short short8;
typedef __attribute__((ext_vector_type(4))) float f32x4;

__device__ __forceinline__ u16 f2bf(float f) {
    u32 u = __float_as_uint(f);
    u32 r = u + 0x7fffu + ((u >> 16) & 1u);
    return (u16)(r >> 16);
}
__device__ __forceinline__ float bfv(u16 v) {
    return __uint_as_float(((u32)v) << 16);
}
__device__ __forceinline__ float ntn(float v) {
    if (isnan(v)) return 0.0f;
    if (isinf(v)) return v > 0.0f ? 3.4028234663852886e38f : -3.4028234663852886e38f;
    return v;
}
__device__ __forceinline__ float wave_sum(float v) {
    #pragma unroll
    for (int o = 32; o > 0; o >>= 1) v += __shfl_xor(v, o, 64);
    return v;
}
// async 16B HBM->LDS: writes ldsbase + lane*16 (wave-uniform base, per-lane gptr)
__device__ __forceinline__ void gload_lds(const u16* g, u16* l) {
    __builtin_amdgcn_global_load_lds(
        (const __attribute__((address_space(1))) u32*)g,
        (__attribute__((address_space(3))) u32*)l, 16, 0, 0);
}

// ============ batched weight convert+transpose: 14 jobs in ONE launch ===============
struct WJob { const float* src; u16* dst; int K; int N; int t0; };
struct WJobs { WJob j[14]; };
__global__ __launch_bounds__(256) void wconv_all(WJobs jobs, int ntiles) {
    int bid = blockIdx.x;
    if (bid >= ntiles) return;
    int ji = 0;
    #pragma unroll 1
    for (int i = 1; i < 14; ++i) if (bid >= jobs.j[i].t0) ji = i;
    const float* in = jobs.j[ji].src;
    u16* out = jobs.j[ji].dst;
    int K = jobs.j[ji].K, N = jobs.j[ji].N;
    int lt = bid - jobs.j[ji].t0;
    int ntx = N >> 5;
    int nb = (lt % ntx) * 32, kb = (lt / ntx) * 32;
    __shared__ float tile[32][33];
    int tx = threadIdx.x & 31, ty = threadIdx.x >> 5;
    #pragma unroll
    for (int r = ty; r < 32; r += 8)
        tile[r][tx] = in[(size_t)(kb + r) * N + nb + tx];
    __syncthreads();
    #pragma unroll
    for (int r = ty; r < 32; r += 8)
        out[(size_t)(nb + r) * K + kb + tx] = f2bf(tile[tx][r]);
}

// ============ MFMA GEMM v3 + XCD-band remap (kept for small M=1024 GEMMs) ===========
// DMA staging + 3-bit XOR chunk swizzle (r9: 0 bank conflicts); XCD remap (r10).
// EPI: 0 none, 1 relu, 2 +res f32, 3 +res bf16.
template<int TM, int TN, int EPI, int WF32, int WBF16>
__global__ __launch_bounds__(256) void gemm_bt(
    const u16* __restrict__ Ab, const u16* __restrict__ Btb,
    float* __restrict__ Cf, u16* __restrict__ Cb, const void* __restrict__ Rg,
    int K, int ldc)
{
    constexpr int WR = TM / 32, WC = TN / 32;
    constexpr int ITA = TM / 32, ITB = TN / 32;
    __shared__ __align__(16) u16 As[TM][64];
    __shared__ __align__(16) u16 Bs[TN][64];
    int tid = threadIdx.x;
    int lane = tid & 63, wave = tid >> 6;
    int quad = lane >> 4, l16 = lane & 15;
    int wm = (wave >> 1) * (TM / 2), wn = (wave & 1) * (TN / 2);

    int gx = gridDim.x, gy = gridDim.y;
    int bx, by;
    if ((gy & 7) == 0) {
        int id = blockIdx.y * gx + blockIdx.x;
        int xcd = id & 7;
        int slot = id >> 3;
        bx = slot % gx;
        by = xcd * (gy >> 3) + slot / gx;
    } else {
        bx = blockIdx.x;
        by = blockIdx.y;
    }
    size_t row0 = (size_t)by * TM;
    size_t col0 = (size_t)bx * TN;

    f32x4 acc[WR][WC];
    #pragma unroll
    for (int i = 0; i < WR; ++i)
        #pragma unroll
        for (int j = 0; j < WC; ++j)
            acc[i][j] = (f32x4){0.f, 0.f, 0.f, 0.f};

    int srow = lane >> 3;
    int c8 = (lane & 7) ^ srow;
    int h8 = l16 & 7;

    for (int k0 = 0; k0 < K; k0 += 64) {
        __syncthreads();
        #pragma unroll
        for (int it = 0; it < ITA; ++it) {
            int g = wave + it * 4;
            gload_lds(Ab + (row0 + g * 8 + srow) * (size_t)K + k0 + c8 * 8, &As[g * 8][0]);
        }
        #pragma unroll
        for (int it = 0; it < ITB; ++it) {
            int g = wave + it * 4;
            gload_lds(Btb + (col0 + g * 8 + srow) * (size_t)K + k0 + c8 * 8, &Bs[g * 8][0]);
        }
        __syncthreads();
        #pragma unroll
        for (int s = 0; s < 2; ++s) {
            int coff = ((s * 4 + quad) ^ h8) * 8;   // full 3-bit XOR (r9-verified)
            short8 af[WR], bf[WC];
            #pragma unroll
            for (int i = 0; i < WR; ++i)
                af[i] = *(short8*)&As[wm + i * 16 + l16][coff];
            #pragma unroll
            for (int j = 0; j < WC; ++j)
                bf[j] = *(short8*)&Bs[wn + j * 16 + l16][coff];
            #pragma unroll
            for (int i = 0; i < WR; ++i)
                #pragma unroll
                for (int j = 0; j < WC; ++j)
                    acc[i][j] = __builtin_amdgcn_mfma_f32_16x16x32_bf16(
                        af[i], bf[j], acc[i][j], 0, 0, 0);
        }
    }
    // C/D layout (on-target verified): col = lane&15, row = quad*4 + reg
    #pragma unroll
    for (int i = 0; i < WR; ++i)
        #pragma unroll
        for (int j = 0; j < WC; ++j)
            #pragma unroll
            for (int reg = 0; reg < 4; ++reg) {
                size_t row = row0 + wm + i * 16 + quad * 4 + reg;
                size_t col = col0 + wn + j * 16 + l16;
                float v = acc[i][j][reg];
                if (EPI == 2) v += ((const float*)Rg)[row * (size_t)ldc + col];
                if (EPI == 3) v += bfv(((const u16*)Rg)[row * (size_t)ldc + col]);
                if (EPI == 1) v = fmaxf(v, 0.f);
                if (WF32)  Cf[row * (size_t)ldc + col] = v;
                if (WBF16) Cb[row * (size_t)ldc + col] = f2bf(v);
            }
}

// ============ counted-pipeline GEMM: 128x128, BK=64, 2 barriers/tile ================
// T4 applied properly (m218: counted-vs-drain0 = +38-73%; drain0 == no pipeline):
// per K-tile: (1) issue 8 gload_lds for tile t+1 into the other LDS buffer FIRST;
// (2) s_waitcnt vmcnt(8) -- counted: the 8 just-issued loads stay IN FLIGHT, only
// tile t's loads (issued one full tile ~2500cyc ago >> 900cyc HBM) must have landed;
// (3) one rendezvous s_barrier (per-wave counter covers its own slice -> whole tile
// staged); (4) full 32-MFMA compute, setprio-wrapped, NO intra-tile barriers (the
// compiler's fine lgkmcnt + 8 resident waves/CU self-schedule; lockstep phase
// barriers in r3 convoyed waves -> 23% MfmaUtil); (5) one end barrier protecting
// the buffer restaged next iter (a wave's ds_reads are consumed by MFMA before it).
// vmcnt(0) only at the last tile. LDS 64KiB -> 2 blocks/CU (cross-block wave mix).
// Same r9-verified XOR swizzle (0 conflicts, refcheck'd rounds 0-3).
// Requires M%128==0, N%128==0, K%64==0 (K>=128), gridDim.y%8==0 (XCD remap).
template<int EPI, int WF32, int WBF16>
__global__ __launch_bounds__(256, 2) void gemm_ct(
    const u16* __restrict__ Ab, const u16* __restrict__ Btb,
    float* __restrict__ Cf, u16* __restrict__ Cb, const void* __restrict__ Rg,
    int K, int ldc)
{
    __shared__ __align__(16) u16 As[2][128][64];
    __shared__ __align__(16) u16 Bs[2][128][64];
    int tid = threadIdx.x;
    int lane = tid & 63, wave = tid >> 6;       // 4 waves: 2M x 2N
    int quad = lane >> 4, l16 = lane & 15;
    int wm = (wave >> 1) * 64, wn = (wave & 1) * 64;

    int gx = gridDim.x, gy = gridDim.y;
    int id = blockIdx.y * gx + blockIdx.x;
    int xcd = id & 7, slot = id >> 3;
    int bx = slot % gx;
    int by = xcd * (gy >> 3) + slot / gx;
    size_t row0 = (size_t)by * 128;
    size_t col0 = (size_t)bx * 128;

    f32x4 acc[4][4];
    #pragma unroll
    for (int i = 0; i < 4; ++i)
        #pragma unroll
        for (int j = 0; j < 4; ++j)
            acc[i][j] = (f32x4){0.f, 0.f, 0.f, 0.f};

    // staging swizzle (r9-verified): physical 16B chunk p of row r holds logical
    // chunk p ^ (r&7)
    int srow = lane >> 3;
    int c8 = (lane & 7) ^ srow;
    int h8 = l16 & 7;
    size_t aoff[4], boff[4];
    #pragma unroll
    for (int it = 0; it < 4; ++it) {
        aoff[it] = (row0 + (size_t)(wave + it * 4) * 8 + srow) * (size_t)K + c8 * 8;
        boff[it] = (col0 + (size_t)(wave + it * 4) * 8 + srow) * (size_t)K + c8 * 8;
    }

    int nt = K >> 6;
    // prologue: stage tile 0 -> buf 0 (8 loads in flight, no wait)
    #pragma unroll
    for (int it = 0; it < 4; ++it)
        gload_lds(Ab + aoff[it], &As[0][(wave + it * 4) * 8][0]);
    #pragma unroll
    for (int it = 0; it < 4; ++it)
        gload_lds(Btb + boff[it], &Bs[0][(wave + it * 4) * 8][0]);

    #pragma unroll 1
    for (int t = 0; t < nt; ++t) {
        int cur = t & 1;
        if (t + 1 < nt) {
            // stage tile t+1 into other buffer (freed by iter t-1's end barrier)
            size_t ko = (size_t)(t + 1) * 64;
            #pragma unroll
            for (int it = 0; it < 4; ++it)
                gload_lds(Ab + aoff[it] + ko, &As[cur ^ 1][(wave + it * 4) * 8][0]);
            #pragma unroll
            for (int it = 0; it < 4; ++it)
                gload_lds(Btb + boff[it] + ko, &Bs[cur ^ 1][(wave + it * 4) * 8][0]);
            __builtin_amdgcn_sched_barrier(0);
            asm volatile("s_waitcnt vmcnt(8)" ::: "memory");   // tile t landed; t+1 in flight
        } else {
            __builtin_amdgcn_sched_barrier(0);
            asm volatile("s_waitcnt vmcnt(0)" ::: "memory");   // final tile only
        }
        __builtin_amdgcn_sched_barrier(0);
        __builtin_amdgcn_s_barrier();                          // rendezvous: tile t staged
        __builtin_amdgcn_sched_barrier(0);
        __builtin_amdgcn_s_setprio(1);
        #pragma unroll
        for (int kh = 0; kh < 2; ++kh) {
            int coff = ((kh * 4 + quad) ^ h8) * 8;
            short8 af[4], bf[4];
            #pragma unroll
            for (int j = 0; j < 4; ++j)
                bf[j] = *(short8*)&Bs[cur][wn + j * 16 + l16][coff];
            #pragma unroll
            for (int i = 0; i < 4; ++i)
                af[i] = *(short8*)&As[cur][wm + i * 16 + l16][coff];
            #pragma unroll
            for (int i = 0; i < 4; ++i)
                #pragma unroll
                for (int j = 0; j < 4; ++j)
                    acc[i][j] = __builtin_amdgcn_mfma_f32_16x16x32_bf16(
                        af[i], bf[j], acc[i][j], 0, 0, 0);
        }
        __builtin_amdgcn_s_setprio(0);
        __builtin_amdgcn_sched_barrier(0);                     // reads done before barrier
        __builtin_amdgcn_s_barrier();                          // frees buf[cur] for restage
    }

    // C/D layout (on-target verified): col = lane&15, row = quad*4 + reg
    #pragma unroll
    for (int i = 0; i < 4; ++i)
        #pragma unroll
        for (int j = 0; j < 4; ++j)
            #pragma unroll
            for (int reg = 0; reg < 4; ++reg) {
                size_t row = row0 + wm + i * 16 + quad * 4 + reg;
                size_t col = col0 + wn + j * 16 + l16;
                float v = acc[i][j][reg];
                if (EPI == 2) v += ((const float*)Rg)[row * (size_t)ldc + col];
                if (EPI == 3) v += bfv(((const u16*)Rg)[row * (size_t)ldc + col]);
                if (EPI == 1) v = fmaxf(v, 0.f);
                if (WF32)  Cf[row * (size_t)ldc + col] = v;
                if (WBF16) Cb[row * (size_t)ldc + col] = f2bf(v);
            }
}

// ============ fused attention per (b,m): all-heads phases, 3 barriers ===============
template<int CTX, int LD>
__global__ __launch_bounds__(256) void attn_fused_kernel(
    const u16* __restrict__ QKVb, const float* __restrict__ maskf, int bm0,
    float* __restrict__ att_sum, u16* __restrict__ ctxb)
{
    __shared__ __align__(16) u16 sQ[16][520];
    __shared__ __align__(16) u16 sK[16][520];
    __shared__ __align__(16) u16 sV[CTX ? 16 : 1][520];
    __shared__ float s_p[H_][16][17];
    int bm_l = blockIdx.x;
    int tid = threadIdx.x;
    int t = tid >> 4, ch = (tid & 15) * 32;
    const u16* base = QKVb + ((size_t)bm_l * T_ + t) * LD;
    #pragma unroll
    for (int c = 0; c < 4; ++c) {
        *(uint4*)&sQ[t][ch + c * 8] = *(const uint4*)(base + ch + c * 8);
        *(uint4*)&sK[t][ch + c * 8] = *(const uint4*)(base + 512 + ch + c * 8);
        if (CTX) *(uint4*)&sV[t][ch + c * 8] = *(const uint4*)(base + 1024 + ch + c * 8);
    }
    __syncthreads();

    int b = (bm0 + bm_l) >> 5;                  // bm = b*NN + m

    #pragma unroll
    for (int r = 0; r < 8; ++r) {
        int h = r;
        int q = (tid >> 4) & 15, k = tid & 15;
        const u32* qu = (const u32*)&sQ[q][0] + h * 32;
        const u32* ku = (const u32*)&sK[k][0] + h * 32;
        float acc = 0.f;
        #pragma unroll
        for (int j = 0; j < 32; ++j) {
            u32 a = qu[j], bb = ku[j];
            acc += bfv((u16)(a & 0xffff)) * bfv((u16)(bb & 0xffff));
            acc += bfv((u16)(a >> 16))    * bfv((u16)(bb >> 16));
        }
        acc *= 0.125f;
        if (maskf[(size_t)(bm0 + bm_l) * T_ + q] == 0.0f) acc = -1e9f;
        s_p[h][q][k] = acc;
    }
    __syncthreads();
    if (tid < 128) {
        int h = tid >> 4, q = tid & 15;
        float mx = -3.4e38f;
        #pragma unroll
        for (int kk = 0; kk < 16; ++kk) mx = fmaxf(mx, s_p[h][q][kk]);
        float e[16], s = 0.f;
        #pragma unroll
        for (int kk = 0; kk < 16; ++kk) { e[kk] = expf(s_p[h][q][kk] - mx); s += e[kk]; }
        float inv = 1.0f / s;
        #pragma unroll
        for (int kk = 0; kk < 16; ++kk) s_p[h][q][kk] = e[kk] * inv;
    }
    __syncthreads();
    #pragma unroll
    for (int r = 0; r < 8; ++r) {
        int h = r;
        int q = (tid >> 4) & 15, k = tid & 15;
        atomicAdd(&att_sum[(((size_t)b * H_ + h) * T_ + q) * T_ + k], s_p[h][q][k]);
    }
    if (CTX) {
        #pragma unroll
        for (int rep = 0; rep < 16; ++rep) {
            int i2 = rep * 256 + tid;           // t*256 + c2, c2 = (h*64+dk)/2
            int tt = i2 >> 8, c2 = i2 & 255;
            int h = c2 >> 5;
            const float* pr = &s_p[h][tt][0];
            float a0 = 0.f, a1 = 0.f;
            #pragma unroll
            for (int kk = 0; kk < 16; ++kk) {
                u32 vv = *((const u32*)&sV[kk][0] + c2);
                float p = pr[kk];
                a0 += p * bfv((u16)(vv & 0xffff));
                a1 += p * bfv((u16)(vv >> 16));
            }
            u32 o = (u32)f2bf(a0) | ((u32)f2bf(a1) << 16);
            *((u32*)(ctxb + ((size_t)bm_l * T_ + tt) * D_) + c2) = o;
        }
    }
}

// ============ fused self-attention + combine + si, one block per (n,h) ==============
__global__ __launch_bounds__(256) void siatt_kernel(
    const float* __restrict__ xemb, const float* __restrict__ att_sum,
    const float* __restrict__ attf, u16* __restrict__ sib)
{
    __shared__ float sX[16][516];
    __shared__ float sS[16][17];
    __shared__ float sA[16][17];
    int n = blockIdx.x >> 3, h = blockIdx.x & 7;
    int tid = threadIdx.x;
    int t = tid >> 4, ch = (tid & 15) * 32;
    const float* src = xemb + ((size_t)n * T_ + t) * D_;
    #pragma unroll
    for (int c = 0; c < 8; ++c)
        *(float4*)&sX[t][ch + c * 4] = *(const float4*)(src + ch + c * 4);
    __syncthreads();
    int q = tid >> 4, k = tid & 15;
    {
        float acc = 0.f;
        for (int d = 0; d < D_; ++d) acc += sX[q][d] * sX[k][d];
        sS[q][k] = acc * 0.04419417382415922f;
    }
    __syncthreads();
    if (tid < T_) {
        float mx = -3.4e38f;
        #pragma unroll
        for (int kk = 0; kk < 16; ++kk) mx = fmaxf(mx, sS[tid][kk]);
        float e[16], s = 0.f;
        #pragma unroll
        for (int kk = 0; kk < 16; ++kk) { e[kk] = expf(sS[tid][kk] - mx); s += e[kk]; }
        float inv = 1.0f / s;
        #pragma unroll
        for (int kk = 0; kk < 16; ++kk) sS[tid][kk] = e[kk] * inv;
    }
    __syncthreads();
    float f = attf[0] * (1.0f / 32.0f);
    sA[q][k] = sS[q][k] + f * att_sum[((size_t)n * H_ + h) * 256 + q * 16 + k];
    __syncthreads();
    #pragma unroll
    for (int rep = 0; rep < 16; ++rep) {
        int i2 = rep * 256 + tid;          // q*256 + d2
        int qq = i2 >> 8, d2 = (i2 & 255) * 2;
        const float* ar = &sA[qq][0];
        float a0 = 0.f, a1 = 0.f;
        #pragma unroll
        for (int tt = 0; tt < 16; ++tt) {
            float p = ar[tt];
            a0 += p * sX[tt][d2];
            a1 += p * sX[tt][d2 + 1];
        }
        u32 o = (u32)f2bf(a0) | ((u32)f2bf(a1) << 16);
        *((u32*)(sib + (size_t)n * T_ * 4096 + (size_t)qq * 4096 + h * 512) + (d2 >> 1)) = o;
    }
}

// ---------------- positional encoding ------------------------------------------------
__global__ void pe_kernel(float* pe) {
    int i = blockIdx.x * blockDim.x + threadIdx.x;
    if (i >= T_ * 256) return;
    int t = i >> 8, j = i & 255;
    float dv = (float)pow(10000.0, (double)j / 256.0);
    float a = (float)t * dv;
    double ad = (double)a;
    pe[t * D_ + 2 * j]     = (float)sin(ad);
    pe[t * D_ + 2 * j + 1] = (float)cos(ad);
}

// ---------------- x features + embed -------------------------------------------------
__global__ void xemb_kernel(const float* x, const float* Wx, const float* bx,
                            const float* pe, float* xemb) {
    int row = blockIdx.x;              // t*N + n
    int t = row / N_, n = row % N_;
    float x0 = x[row * 6 + 0], x1 = x[row * 6 + 1];
    float x2 = x[row * 6 + 2], x3 = x[row * 6 + 3];
    float x4 = x[row * 6 + 4], x5 = x[row * 6 + 5];
    float vel = sqrtf(x2 * x2 + x3 * x3);
    float ang = atanf(x5 / x4);
    float f0 = ntn(x0), f1 = ntn(x1), f2 = ntn(vel), f3 = ntn(ang);
    for (int d = threadIdx.x; d < D_; d += blockDim.x) {
        xemb[((size_t)n * T_ + t) * D_ + d] =
            f0 * Wx[0 * D_ + d] + f1 * Wx[1 * D_ + d]
          + f2 * Wx[2 * D_ + d] + f3 * Wx[3 * D_ + d]
          + bx[d] + pe[t * D_ + d];
    }
}

// ---------------- neighbor features + mask -------------------------------------------
__global__ void nbr_kernel(const float* x, const float* nbr, float* nf, float* maskf) {
    int idx = blockIdx.x * blockDim.x + threadIdx.x;   // t*N*NN + n*NN + m
    if (idx >= T_ * N_ * NN_) return;
    int m = idx % NN_;
    int tn = idx / NN_;
    int n = tn % N_, t = tn / N_;
    float px = x[((size_t)t * N_ + n) * 6 + 0];
    float py = x[((size_t)t * N_ + n) * 6 + 1];
    float vx, vy;
    if (t == 0) {
        vx = x[((size_t)1 * N_ + n) * 6 + 2];
        vy = x[((size_t)1 * N_ + n) * 6 + 3];
    } else {
        vx = px - x[((size_t)(t - 1) * N_ + n) * 6 + 0];
        vy = py - x[((size_t)(t - 1) * N_ + n) * 6 + 1];
    }
    float nx  = nbr[(size_t)idx * 4 + 0], ny  = nbr[(size_t)idx * 4 + 1];
    float nvx = nbr[(size_t)idx * 4 + 2], nvy = nbr[(size_t)idx * 4 + 3];
    float dpx = nx - px, dpy = ny - py;
    float dvx = nvx - vx, dvy = nvy - vy;
    float dist = sqrtf(dpx * dpx + dpy * dpy);
    maskf[((size_t)n * NN_ + m) * T_ + t] = (dist <= 2.0f) ? 1.0f : 0.0f;
    float vn = sqrtf(vx * vx + vy * vy);
    float bearing = (dpx * vx + dpy * vy) / (dist * vn);
    if (isnan(bearing)) bearing = 0.0f;
    float dvn = sqrtf(dvx * dvx + dvy * dvy);
    float tau = -(dpx * dvx + dpy * dvy) / dvn;
    if (isnan(tau)) tau = 0.0f;
    tau = fminf(fmaxf(tau, 0.0f), 7.0f);
    float mx_ = dpx + tau * dvx, my_ = dpy + tau * dvy;
    float mpd = sqrtf(mx_ * mx_ + my_ * my_);
    nf[(size_t)idx * 3 + 0] = ntn(dist);
    nf[(size_t)idx * 3 + 1] = ntn(bearing);
    nf[(size_t)idx * 3 + 2] = ntn(mpd);
}

// ---------------- neighbor embed: bf16 n_emb only ------------------------------------
__global__ void nemb_kernel(const float* nf, const float* Wn, const float* bn,
                            const float* pe, u16* Ab) {
    int row = blockIdx.x;              // (b*NN+m)*T + t
    int t = row % T_;
    int bm = row / T_;
    int m = bm % NN_, b = bm / NN_;
    size_t nfrow = (((size_t)t * N_ + b) * NN_ + m) * 3;
    float f0 = nf[nfrow], f1 = nf[nfrow + 1], f2 = nf[nfrow + 2];
    for (int d = threadIdx.x; d < D_; d += blockDim.x) {
        float v = f0 * Wn[d] + f1 * Wn[D_ + d] + f2 * Wn[2 * D_ + d]
                + bn[d] + pe[t * D_ + d];
        Ab[(size_t)row * D_ + d] = f2bf(v);
    }
}

// ---------------- LayerNorm, one wave per row; input f32 or bf16; dual out -----------
template<int INBF>
__global__ __launch_bounds__(256) void ln_kernel(
    const void* X, const float* g, const float* b, float* outF, u16* outB, int nrows) {
    int row = blockIdx.x * 4 + (threadIdx.x >> 6);
    if (row >= nrows) return;
    int lane = threadIdx.x & 63;
    float v[8];
    float s = 0.f;
    #pragma unroll
    for (int r = 0; r < 8; ++r) {
        int d = lane + r * 64;
        v[r] = INBF ? bfv(((const u16*)X)[(size_t)row * D_ + d])
                    : ((const float*)X)[(size_t)row * D_ + d];
        s += v[r];
    }
    s = wave_sum(s);
    float mean = s * (1.0f / 512.0f);
    float vs = 0.f;
    #pragma unroll
    for (int r = 0; r < 8; ++r) { float d = v[r] - mean; vs += d * d; }
    vs = wave_sum(vs);
    float rstd = rsqrtf(vs * (1.0f / 512.0f) + 1e-5f);
    #pragma unroll
    for (int r = 0; r < 8; ++r) {
        int d = lane + r * 64;
        float o = (v[r] - mean) * rstd * g[d] + b[d];
        if (outF) outF[(size_t)row * D_ + d] = o;
        if (outB) outB[(size_t)row * D_ + d] = f2bf(o);
    }
}

// ---------------- prediction head + broadcast fused (f32 out) ------------------------
__global__ void predbcast_kernel(const float* xemb, const float* Wp, const float* bp,
                                 float* out) {
    int idx = blockIdx.x * blockDim.x + threadIdx.x;   // (n*T+t)*2 + c
    if (idx >= N_ * T_ * 2) return;
    int c = idx & 1;
    int nt = idx >> 1;
    int n = nt / T_, t = nt % T_;
    float acc = bp[c];
    for (int j = 0; j < D_; ++j) acc += xemb[(size_t)nt * D_ + j] * Wp[(size_t)j * 2 + c];
    #pragma unroll
    for (int p = 0; p < NPRED_; ++p)
        out[(((size_t)p * T_ + t) * N_ + n) * 2 + c] = acc;
}

extern "C" void kernel_launch(void* const* d_in, const int* in_sizes, int n_in,
                              void* d_out, int out_size, void* d_ws, size_t ws_size,
                              hipStream_t stream) {
    (void)in_sizes; (void)n_in; (void)out_size; (void)ws_size;

    const float* x    = (const float*)d_in[0];
    const float* nbr  = (const float*)d_in[1];
    const float* attf = (const float*)d_in[2];
    const float* Wx   = (const float*)d_in[3];
    const float* bx   = (const float*)d_in[4];
    const float* Wn   = (const float*)d_in[5];
    const float* bn   = (const float*)d_in[6];
    const float* Wp   = (const float*)d_in[7];
    const float* bp   = (const float*)d_in[8];
    const float* WQ   = (const float*)d_in[9];
    const float* WK   = (const float*)d_in[10];
    const float* WV   = (const float*)d_in[11];
    const float* Wfc  = (const float*)d_in[12];
    const float* mlng = (const float*)d_in[13];
    const float* mlnb = (const float*)d_in[14];
    const float* WSI  = (const float*)d_in[15];
    const float* fsw1 = (const float*)d_in[16];
    const float* fsw2 = (const float*)d_in[17];
    const float* fsg  = (const float*)d_in[18];
    const float* fsb  = (const float*)d_in[19];
    const float* fiw1 = (const float*)d_in[20];
    const float* fiw2 = (const float*)d_in[21];
    const float* fig  = (const float*)d_in[22];
    const float* fib  = (const float*)d_in[23];

    char* w = (char*)d_ws;
    size_t off = 0;
    auto alloc = [&](size_t bytes) -> void* {
        void* p = w + off;
        off = (off + bytes + 255) & ~(size_t)255;
        return p;
    };
    const size_t MiB = 1024 * 1024;

    const int BM = N_ * NN_;          // 2048 (b,m) pairs
    const int ROWS_I = BM * T_;       // 32768 neighbor rows
    const int CB = 1024;              // bm per chunk (NCH=2, l=0 only)
    const int RC = CB * T_;           // 16384 rows per chunk
    const int NCH = ROWS_I / RC;      // 2

    float* pe      = (float*)alloc((size_t)T_ * D_ * 4);
    float* xemb    = (float*)alloc((size_t)N_ * T_ * D_ * 4);
    float* nf      = (float*)alloc((size_t)T_ * N_ * NN_ * 3 * 4);
    float* maskf   = (float*)alloc((size_t)BM * T_ * 4);
    u16*   Ab      = (u16*)alloc((size_t)ROWS_I * D_ * 2);     // n_emb bf16  32 MiB
    u16* tQKV[2], *tWSI[2], *tfs1[2], *tfs2[2];
    for (int l = 0; l < 2; ++l) {
        tQKV[l] = (u16*)alloc((size_t)1536 * 512 * 2);
        tWSI[l] = (u16*)alloc((size_t)512 * 4096 * 2);
        tfs1[l] = (u16*)alloc((size_t)2048 * 512 * 2);
        tfs2[l] = (u16*)alloc((size_t)512 * 2048 * 2);
    }
    u16* tWfc = (u16*)alloc((size_t)512 * 512 * 2);
    u16* tfi1 = (u16*)alloc((size_t)2048 * 512 * 2);
    u16* tfi2 = (u16*)alloc((size_t)512 * 2048 * 2);
    // scratch union: l0 chunk: QKVb 48 + ctxb 16 | hid 64 ; l1: QK full 64 MiB
    char* SCR  = (char*)alloc(64 * MiB);
    u16*   QKVb = (u16*)SCR;
    u16*   ctxb = (u16*)(SCR + 48 * MiB);
    u16*   hid  = (u16*)SCR;
    u16*   BbA    = (u16*)alloc((size_t)RC * D_ * 2);  // pre-LN bf16 chunk    16 MiB
    u16*   Bb_res = (u16*)alloc((size_t)RC * D_ * 2);  // res_inter bf16       16 MiB
    float* att_sum = (float*)alloc((size_t)N_ * H_ * 256 * 4);
    u16*   sib     = (u16*)alloc((size_t)N_ * T_ * 4096 * 2);  // 8 MiB
    float* xnew    = (float*)alloc((size_t)N_ * T_ * D_ * 4);
    u16*   xnb     = (u16*)alloc((size_t)N_ * T_ * D_ * 2);
    // total ~170 MiB

    // ---- batched weight conversion: 14 jobs, one launch ----
    WJobs jobs;
    int ntiles = 0;
    auto addJob = [&](int idx, const float* src, u16* dst, int K, int N) {
        jobs.j[idx] = {src, dst, K, N, ntiles};
        ntiles += (N >> 5) * (K >> 5);
    };
    addJob(0,  WQ,                            tQKV[0],              512, 512);
    addJob(1,  WK,                            tQKV[0] + 512 * 512,  512, 512);
    addJob(2,  WV,                            tQKV[0] + 1024 * 512, 512, 512);   // dead at l=1
    addJob(3,  WQ + (size_t)512 * 512,        tQKV[1],              512, 512);
    addJob(4,  WK + (size_t)512 * 512,        tQKV[1] + 512 * 512,  512, 512);
    addJob(5,  Wfc,                           tWfc,                 512, 512);
    addJob(6,  WSI,                           tWSI[0],              4096, 512);
    addJob(7,  WSI + (size_t)4096 * 512,      tWSI[1],              4096, 512);
    addJob(8,  fsw1,                          tfs1[0],              512, 2048);
    addJob(9,  fsw1 + (size_t)512 * 2048,     tfs1[1],              512, 2048);
    addJob(10, fsw2,                          tfs2[0],              2048, 512);
    addJob(11, fsw2 + (size_t)2048 * 512,     tfs2[1],              2048, 512);
    addJob(12, fiw1,                          tfi1,                 512, 2048);
    addJob(13, fiw2,                          tfi2,                 2048, 512);
    wconv_all<<<ntiles, 256, 0, stream>>>(jobs, ntiles);

    pe_kernel<<<16, 256, 0, stream>>>(pe);
    xemb_kernel<<<T_ * N_, 256, 0, stream>>>(x, Wx, bx, pe, xemb);
    nbr_kernel<<<(T_ * N_ * NN_ + 255) / 256, 256, 0, stream>>>(x, nbr, nf, maskf);
    nemb_kernel<<<BM * T_, 256, 0, stream>>>(nf, Wn, bn, pe, Ab);

    for (int l = 0; l < L_; ++l) {
        hipMemsetAsync(att_sum, 0, (size_t)N_ * H_ * 256 * 4, stream);
        if (l == 0) {
            for (int c = 0; c < NCH; ++c) {
                u16* Acb = Ab + (size_t)c * RC * D_;
                // QKV fused GEMM: N=1536 (1536 blocks = 3 exact rounds @2/CU)
                gemm_ct<0, 0, 1><<<dim3(12, RC / 128), 256, 0, stream>>>(
                    Acb, tQKV[0], nullptr, QKVb, nullptr, 512, 1536);
                attn_fused_kernel<1, 1536><<<CB, 256, 0, stream>>>(
                    QKVb, maskf, c * CB, att_sum, ctxb);
                // fc + residual(n_emb bf16) -> pre-LN bf16 (512 blocks = 1 round)
                gemm_ct<3, 0, 1><<<dim3(4, RC / 128), 256, 0, stream>>>(
                    ctxb, tWfc, nullptr, BbA, Acb, 512, 512);
                ln_kernel<1><<<RC / 4, 256, 0, stream>>>(
                    BbA, mlng, mlnb, nullptr, Bb_res, RC);   // res_inter bf16
                // ffi1 relu: N=2048 (2048 blocks = 4 exact rounds)
                gemm_ct<1, 0, 1><<<dim3(16, RC / 128), 256, 0, stream>>>(
                    Bb_res, tfi1, nullptr, hid, nullptr, 512, 2048);
                // ffi2 + residual(res_inter bf16) -> pre-LN bf16 (512 blocks)
                gemm_ct<3, 0, 1><<<dim3(4, RC / 128), 256, 0, stream>>>(
                    hid, tfi2, nullptr, BbA, Bb_res, 2048, 512);
                ln_kernel<1><<<RC / 4, 256, 0, stream>>>(
                    BbA, fig, fib, nullptr, Acb, RC);        // new n_emb (bf16)
            }
        } else {
            // l=1: unchunked QK (N=1024, ldc=1024; 64 MiB = SCR): 2048 blocks
            gemm_ct<0, 0, 1><<<dim3(8, ROWS_I / 128), 256, 0, stream>>>(
                Ab, tQKV[1], nullptr, QKVb, nullptr, 512, 1024);
            attn_fused_kernel<0, 1024><<<BM, 256, 0, stream>>>(
                QKVb, maskf, 0, att_sum, nullptr);
        }

        // ---- self-attention + si + ffs (updates xemb; f32 chain unchanged) ----
        siatt_kernel<<<N_ * H_, 256, 0, stream>>>(xemb, att_sum, attf, sib);
        gemm_bt<32, 64, 0, 1, 1><<<dim3(8, 32), 256, 0, stream>>>(
            sib, tWSI[l], xnew, xnb, nullptr, 4096, 512);
        gemm_bt<32, 64, 1, 0, 1><<<dim3(32, 32), 256, 0, stream>>>(
            xnb, tfs1[l], nullptr, hid, nullptr, 512, 2048);
        gemm_bt<32, 64, 2, 1, 0><<<dim3(8, 32), 256, 0, stream>>>(
            hid, tfs2[l], xemb, nullptr, xnew, 2048, 512);
        ln_kernel<0><<<(N_ * T_) / 4, 256, 0, stream>>>(
            xemb, fsg + l * D_, fsb + l * D_, xemb, nullptr, N_ * T_);
    }

    predbcast_kernel<<<(N_ * T_ * 2 + 255) / 256, 256, 0, stream>>>(
        xemb, Wp, bp, (float*)d_out);
}